// Round 8
// baseline (677.531 us; speedup 1.0000x reference)
//
#include <hip/hip_runtime.h>
#include <math.h>

#define D128 128
#define NM_ 1043
#define ND_ 2166
#define EM_ 300000
#define ED_ 600000
#define NBH 64              // chunks per view (hist + fill)
#define NMAX 2176
#define NTOT 6418           // 2*1043 + 2*2166
#define ETOT 1800000
#define CHUNK 64            // dst nodes per aggL block

struct ViewArgs {
    const int* edge[4];
    const float* w[4];
    int n[4], E[4];
    int cumn[5];
    int cumE[5];
    int rpo[4];
};

struct BiasArr { const float* b[4]; };

// ---------------------------------------------------------------------------
// CSR build, pass 1: per-chunk privatized histograms (LDS atomics only)
// ---------------------------------------------------------------------------
__global__ __launch_bounds__(1024) void hist_b(ViewArgs va, int* __restrict__ pcnt,
                                               float* __restrict__ pdeg) {
    __shared__ int lc[NMAX];
    __shared__ float ld[NMAX];
    const int view = blockIdx.x >> 6, vb = blockIdx.x & 63;
    const int n = va.n[view], E = va.E[view];
    const int* edge = va.edge[view];
    const float* w = va.w[view];
    for (int i = threadIdx.x; i < n; i += 1024) { lc[i] = 0; ld[i] = 0.f; }
    __syncthreads();
    const int per = (E + NBH - 1) / NBH;
    const int b = vb * per, e = min(E, b + per);
    for (int i = b + threadIdx.x; i < e; i += 1024) {
        int dst = edge[E + i];
        atomicAdd(&lc[dst], 1);
        atomicAdd(&ld[dst], w[i]);
    }
    __syncthreads();
    int* pc = pcnt + (size_t)NBH * va.cumn[view] + (size_t)vb * n;
    float* pd = pdeg + (size_t)NBH * va.cumn[view] + (size_t)vb * n;
    for (int i = threadIdx.x; i < n; i += 1024) { pc[i] = lc[i]; pd[i] = ld[i]; }
}

// ---------------------------------------------------------------------------
// merged colred + scan + cum: one block per view
// ---------------------------------------------------------------------------
__global__ __launch_bounds__(1024) void csrmeta_b(ViewArgs va, const int* __restrict__ pcnt,
                                                  const float* __restrict__ pdeg,
                                                  float* __restrict__ dinv,
                                                  int* __restrict__ rowptr,
                                                  int* __restrict__ cum) {
    __shared__ int lcnt[NMAX];
    __shared__ int wsum[16];
    const int view = blockIdx.x;
    const int n = va.n[view];
    const int* pc = pcnt + (size_t)NBH * va.cumn[view];
    const float* pd = pdeg + (size_t)NBH * va.cumn[view];
    int* rp = rowptr + va.rpo[view];
    float* dv = dinv + va.cumn[view];
    int* cm = cum + (size_t)NBH * va.cumn[view];
    const int tid = threadIdx.x;
    for (int i = tid; i < n; i += 1024) {
        int c = 0;
        float dg = 0.f;
        for (int b = 0; b < NBH; ++b) {
            c += pc[(size_t)b * n + i];
            dg += pd[(size_t)b * n + i];
        }
        lcnt[i] = c;
        dv[i] = dg > 0.f ? 1.0f / sqrtf(dg) : 0.f;
    }
    __syncthreads();
    const int per = (n + 1023) / 1024;
    const int b0 = min(n, tid * per), e0 = min(n, b0 + per);
    int s = 0;
    for (int i = b0; i < e0; ++i) s += lcnt[i];
    const int lane = tid & 63, wid = tid >> 6;
    int sc = s;
    for (int off = 1; off < 64; off <<= 1) {
        int t = __shfl_up(sc, off);
        if (lane >= off) sc += t;
    }
    if (lane == 63) wsum[wid] = sc;
    __syncthreads();
    int wbase = 0;
    for (int wv = 0; wv < wid; ++wv) wbase += wsum[wv];
    int run = wbase + sc - s;
    if (tid == 0) rp[0] = 0;
    for (int i = b0; i < e0; ++i) {
        int c = lcnt[i];
        lcnt[i] = run;
        run += c;
        rp[i + 1] = run;
    }
    __syncthreads();
    for (int i = tid; i < n; i += 1024) {
        int r = lcnt[i];
        for (int b = 0; b < NBH; ++b) {
            cm[(size_t)b * n + i] = r;
            r += pc[(size_t)b * n + i];
        }
    }
}

// CSR build pass 2: place (src, norm) pairs; int2 writes
__global__ __launch_bounds__(1024) void fill2_b(ViewArgs va, const float* __restrict__ dinv,
                                                const int* __restrict__ cum,
                                                int2* __restrict__ spair) {
    __shared__ int lc[NMAX];
    const int view = blockIdx.x >> 6, vb = blockIdx.x & 63;
    const int n = va.n[view], E = va.E[view];
    const int* edge = va.edge[view];
    const float* w = va.w[view];
    const int* cm = cum + (size_t)NBH * va.cumn[view] + (size_t)vb * n;
    const float* dv = dinv + va.cumn[view];
    int2* sp = spair + va.cumE[view];
    for (int i = threadIdx.x; i < n; i += 1024) lc[i] = cm[i];
    __syncthreads();
    const int per = (E + NBH - 1) / NBH;
    const int b = vb * per, e = min(E, b + per);
    for (int i = b + threadIdx.x; i < e; i += 1024) {
        int src = edge[i];
        int dst = edge[E + i];
        int pos = atomicAdd(&lc[dst], 1);
        float nrm = dv[src] * w[i] * dv[dst];
        sp[pos] = make_int2(src, __float_as_int(nrm));
    }
}

// ---------------------------------------------------------------------------
// LDS-staged aggregation + bias + relu.
// Block = 256 thr. Grid over (view, col-group, 64-node chunk). The block
// stages h's CG columns for ALL n rows of its view column-major into LDS
// (NPAD = n padded to 1 mod 32 -> bank=(col+src)%32, ~2-way worst), then
// each CG-thread col-group walks consecutive nodes' CSR lists:
// per edge = broadcast int2 + ds_read_b32 + fma.
// ---------------------------------------------------------------------------
template <int CG, int NPAD>
__global__ __launch_bounds__(256) void aggL_b(ViewArgs va, const int2* __restrict__ sp_all,
                                              const int* __restrict__ rowptr,
                                              const float* __restrict__ h, BiasArr ba,
                                              float* __restrict__ outbuf,
                                              int vlo, int bpv, int nchunks) {
    extern __shared__ float hs[];
    const int view = vlo + blockIdx.x / bpv;
    const int lb = blockIdx.x % bpv;
    const int cg = lb / nchunks;
    const int chunk = lb - cg * nchunks;
    const int n = va.n[view];
    const float* hb = h + (size_t)va.cumn[view] * D128 + cg * CG;
    const int tid = threadIdx.x;
    // stage: column-major hs[c*NPAD + row]
    constexpr int LPR = CG / 4;          // float4 lanes per row
    constexpr int RPP = 256 / LPR;       // rows per pass
    const int r0 = tid / LPR;
    const int cq = (tid % LPR) * 4;
    for (int base = 0; base < n; base += RPP) {
        int row = base + r0;
        if (row < n) {
            float4 v = *(const float4*)(hb + (size_t)row * D128 + cq);
            hs[(cq + 0) * NPAD + row] = v.x;
            hs[(cq + 1) * NPAD + row] = v.y;
            hs[(cq + 2) * NPAD + row] = v.z;
            hs[(cq + 3) * NPAD + row] = v.w;
        }
    }
    __syncthreads();
    constexpr int NDG = 256 / CG;        // col-groups per block
    constexpr int NPG = CHUNK / NDG;     // nodes per col-group
    const int dg = tid / CG;
    const int col = tid % CG;
    const int* rp = rowptr + va.rpo[view];
    const int2* sp = sp_all + va.cumE[view];
    const float* hcol = hs + col * NPAD;
    const int colg = cg * CG + col;
    const float bcol = ba.b[view][colg];
    float* ob = outbuf + (size_t)va.cumn[view] * D128 + colg;
    int node = chunk * CHUNK + dg * NPG;
    for (int k = 0; k < NPG; ++k, ++node) {
        if (node >= n) break;
        const int beg = rp[node], end = rp[node + 1];
        float a0 = 0.f, a1 = 0.f, a2 = 0.f, a3 = 0.f;
        int i = beg;
        for (; i + 4 <= end; i += 4) {
            int2 p0 = sp[i], p1 = sp[i + 1], p2 = sp[i + 2], p3 = sp[i + 3];
            a0 = fmaf(__int_as_float(p0.y), hcol[p0.x], a0);
            a1 = fmaf(__int_as_float(p1.y), hcol[p1.x], a1);
            a2 = fmaf(__int_as_float(p2.y), hcol[p2.x], a2);
            a3 = fmaf(__int_as_float(p3.y), hcol[p3.x], a3);
        }
        for (; i < end; ++i)
            a0 = fmaf(__int_as_float(sp[i].y), hcol[sp[i].x], a0);
        float v = (a0 + a1) + (a2 + a3);
        ob[(size_t)node * D128] = fmaxf(v + bcol, 0.f);
    }
}

// fallback (r5-proven): one block (128 thr) per node, L2 gathers
__global__ __launch_bounds__(128) void agg_b(ViewArgs va, const int2* __restrict__ spair,
                                             const int* __restrict__ rowptr,
                                             const float* __restrict__ h, BiasArr ba,
                                             float* __restrict__ outbuf) {
    const int nf = blockIdx.x;
    int view = 0;
    while (view < 3 && nf >= va.cumn[view + 1]) ++view;
    const int ln = nf - va.cumn[view];
    const int* rp = rowptr + va.rpo[view];
    const int beg = rp[ln], end = rp[ln + 1];
    const int2* sp = spair + va.cumE[view];
    const float* hb = h + (size_t)va.cumn[view] * D128;
    const int tid = threadIdx.x;
    float a0 = 0.f, a1 = 0.f, a2 = 0.f, a3 = 0.f;
    int i = beg;
    for (; i + 4 <= end; i += 4) {
        int2 p0 = sp[i], p1 = sp[i + 1], p2 = sp[i + 2], p3 = sp[i + 3];
        a0 = fmaf(__int_as_float(p0.y), hb[(size_t)p0.x * D128 + tid], a0);
        a1 = fmaf(__int_as_float(p1.y), hb[(size_t)p1.x * D128 + tid], a1);
        a2 = fmaf(__int_as_float(p2.y), hb[(size_t)p2.x * D128 + tid], a2);
        a3 = fmaf(__int_as_float(p3.y), hb[(size_t)p3.x * D128 + tid], a3);
    }
    for (; i < end; ++i)
        a0 = fmaf(__int_as_float(sp[i].y), hb[(size_t)sp[i].x * D128 + tid], a0);
    float v = (a0 + a1) + (a2 + a3);
    outbuf[(size_t)nf * D128 + tid] = fmaxf(v + ba.b[view][tid], 0.f);
}

// ---------------------------------------------------------------------------
// unified multi-segment GEMM: C[M,N] = A[M,K] @ W[N,K]^T (+bias, relu)
// mode 0: plain A; mode 1: miRNA concat-on-the-fly; mode 2: drug concat.
// ---------------------------------------------------------------------------
struct GSeg {
    const float* A;
    const float* W;
    const float* bias;
    float* C;
    int M, N, K, rowblks, blk0, relu, mode;
};
struct GArgs {
    GSeg s[4];
    int nseg;
    const float* l1;
    const float* l2;
    const float* scales;
};

__global__ __launch_bounds__(256) void gemm_b(GArgs ga) {
    __shared__ float xs[32 * 64];
    __shared__ float wsm[128 * 64];
    int si = 0;
    while (si + 1 < ga.nseg && (int)blockIdx.x >= ga.s[si + 1].blk0) ++si;
    const GSeg S = ga.s[si];
    const int lb = blockIdx.x - S.blk0;
    const int rb = lb % S.rowblks, cb = lb / S.rowblks;
    const int row0 = rb * 32, col0 = cb * 128;
    const int tid = threadIdx.x;
    const int r0 = (tid >> 5) << 2;
    const int c0 = tid & 31;
    const int csw = (c0 & 7) << 2;
    float acc[4][4] = {};
    for (int kc = 0; kc < S.K; kc += 64) {
#pragma unroll
        for (int it = 0; it < 2; ++it) {
            int idx = tid + it * 256;
            int r = idx >> 4, k4 = (idx & 15) << 2;
            int gr = row0 + r;
            if (gr > S.M - 1) gr = S.M - 1;
            float4 v;
            if (S.mode == 0) {
                v = *(const float4*)(S.A + (size_t)gr * S.K + kc + k4);
            } else {
                int kk = kc + k4;
                int c = kk >> 7, j = kk & 127;
                if (S.mode == 1) {
                    const float* base = (c == 0) ? ga.l1 : (c == 1) ? ga.l2
                                       : (c == 2) ? ga.l1 + 133504 : ga.l2 + 133504;
                    v = *(const float4*)(base + (size_t)gr * 128 + j);
                    float s = ga.scales[c];
                    v.x *= s; v.y *= s; v.z *= s; v.w *= s;
                } else {
                    const float* bp = c ? ga.l2 : ga.l1;
                    float4 va4 = *(const float4*)(bp + 267008 + (size_t)gr * 128 + j);
                    float4 vb4 = *(const float4*)(bp + 544256 + (size_t)gr * 128 + j);
                    float s = ga.scales[4 + c];
                    v.x = s * (va4.x + vb4.x);
                    v.y = s * (va4.y + vb4.y);
                    v.z = s * (va4.z + vb4.z);
                    v.w = s * (va4.w + vb4.w);
                }
            }
            *(float4*)(xs + r * 64 + k4) = v;
        }
#pragma unroll
        for (int it = 0; it < 8; ++it) {
            int idx = tid + it * 256;
            int c = idx >> 4, k4 = (idx & 15) << 2;
            *(float4*)(wsm + c * 64 + (k4 ^ ((c & 7) << 2))) =
                *(const float4*)(S.W + (size_t)(col0 + c) * S.K + kc + k4);
        }
        __syncthreads();
#pragma unroll
        for (int k4 = 0; k4 < 64; k4 += 4) {
            float4 a0 = *(const float4*)(xs + (r0 + 0) * 64 + k4);
            float4 a1 = *(const float4*)(xs + (r0 + 1) * 64 + k4);
            float4 a2 = *(const float4*)(xs + (r0 + 2) * 64 + k4);
            float4 a3 = *(const float4*)(xs + (r0 + 3) * 64 + k4);
            const int sk = k4 ^ csw;
            float4 w0 = *(const float4*)(wsm + (c0 + 0) * 64 + sk);
            float4 w1 = *(const float4*)(wsm + (c0 + 32) * 64 + sk);
            float4 w2 = *(const float4*)(wsm + (c0 + 64) * 64 + sk);
            float4 w3 = *(const float4*)(wsm + (c0 + 96) * 64 + sk);
#define FMA4(i, av)                                                   \
            acc[i][0] = fmaf(av.x, w0.x, acc[i][0]); acc[i][0] = fmaf(av.y, w0.y, acc[i][0]); \
            acc[i][0] = fmaf(av.z, w0.z, acc[i][0]); acc[i][0] = fmaf(av.w, w0.w, acc[i][0]); \
            acc[i][1] = fmaf(av.x, w1.x, acc[i][1]); acc[i][1] = fmaf(av.y, w1.y, acc[i][1]); \
            acc[i][1] = fmaf(av.z, w1.z, acc[i][1]); acc[i][1] = fmaf(av.w, w1.w, acc[i][1]); \
            acc[i][2] = fmaf(av.x, w2.x, acc[i][2]); acc[i][2] = fmaf(av.y, w2.y, acc[i][2]); \
            acc[i][2] = fmaf(av.z, w2.z, acc[i][2]); acc[i][2] = fmaf(av.w, w2.w, acc[i][2]); \
            acc[i][3] = fmaf(av.x, w3.x, acc[i][3]); acc[i][3] = fmaf(av.y, w3.y, acc[i][3]); \
            acc[i][3] = fmaf(av.z, w3.z, acc[i][3]); acc[i][3] = fmaf(av.w, w3.w, acc[i][3]);
            FMA4(0, a0) FMA4(1, a1) FMA4(2, a2) FMA4(3, a3)
#undef FMA4
        }
        __syncthreads();
    }
#pragma unroll
    for (int i = 0; i < 4; ++i) {
        int gr = row0 + r0 + i;
        if (gr < S.M) {
#pragma unroll
            for (int j = 0; j < 4; ++j) {
                int gc = col0 + c0 + 32 * j;
                float v = acc[i][j];
                if (S.bias) v += S.bias[gc];
                if (S.relu) v = fmaxf(v, 0.f);
                S.C[(size_t)gr * S.N + gc] = v;
            }
        }
    }
}

// ---------------------------------------------------------------------------
// channel sums + attention scales
// ---------------------------------------------------------------------------
struct SumArgs {
    const float* p[8];
    int cnt[8];
};

__global__ __launch_bounds__(256) void sum8_kernel(SumArgs args, float* __restrict__ sums) {
    __shared__ float red[256];
    const int ch = blockIdx.y;
    const float* x = args.p[ch];
    const int count = args.cnt[ch];
    float s = 0.f;
    for (int i = blockIdx.x * 256 + threadIdx.x; i < count; i += gridDim.x * 256) s += x[i];
    red[threadIdx.x] = s;
    __syncthreads();
    for (int off = 128; off > 0; off >>= 1) {
        if (threadIdx.x < off) red[threadIdx.x] += red[threadIdx.x + off];
        __syncthreads();
    }
    if (threadIdx.x == 0) atomicAdd(&sums[ch], red[0]);
}

__global__ void att_kernel(const float* __restrict__ sums,
                           const float* __restrict__ mW1, const float* __restrict__ mb1,
                           const float* __restrict__ mW2, const float* __restrict__ mb2,
                           const float* __restrict__ dW1, const float* __restrict__ db1,
                           const float* __restrict__ dW2, const float* __restrict__ db2,
                           float* __restrict__ scales) {
    if (threadIdx.x != 0 || blockIdx.x != 0) return;
    float mean[4], a[4];
    const float invM = 1.0f / (128.f * (float)NM_);
    for (int c = 0; c < 4; ++c) mean[c] = sums[c] * invM;
    for (int i = 0; i < 4; ++i) {
        float v = mb1[i];
        for (int j = 0; j < 4; ++j) v += mW1[i * 4 + j] * mean[j];
        a[i] = fmaxf(v, 0.f);
    }
    for (int c = 0; c < 4; ++c) {
        float v = mb2[c];
        for (int j = 0; j < 4; ++j) v += mW2[c * 4 + j] * a[j];
        scales[c] = 1.f / (1.f + expf(-v));
    }
    const float invD = 1.0f / (128.f * (float)ND_);
    float md[2] = {(sums[4] + sums[6]) * invD, (sums[5] + sums[7]) * invD};
    float ad[2];
    for (int i = 0; i < 2; ++i) {
        float v = db1[i];
        for (int j = 0; j < 2; ++j) v += dW1[i * 2 + j] * md[j];
        ad[i] = fmaxf(v, 0.f);
    }
    for (int c = 0; c < 2; ++c) {
        float v = db2[c];
        for (int j = 0; j < 2; ++j) v += dW2[c * 2 + j] * ad[j];
        scales[4 + c] = 1.f / (1.f + expf(-v));
    }
}

// ---------------------------------------------------------------------------
extern "C" void kernel_launch(void* const* d_in, const int* in_sizes, int n_in,
                              void* d_out, int out_size, void* d_ws, size_t ws_size,
                              hipStream_t stream) {
    const float* mirna_x = (const float*)d_in[0];
    const float* drug_x  = (const float*)d_in[1];
    float* out = (float*)d_out;
    (void)in_sizes; (void)n_in; (void)out_size; (void)ws_size;

    char* ws = (char*)d_ws;
    auto AL = [](size_t x) { return (x + 255) & ~(size_t)255; };
    size_t o = 0;
    int2* spair = (int2*)(ws + o);   o += AL((size_t)ETOT * 8);
    int* rowptr = (int*)(ws + o);    o += AL((size_t)(NTOT + 4) * 4);
    float* dinv = (float*)(ws + o);  o += AL((size_t)NTOT * 4);
    float* sums = (float*)(ws + o);  o += 256;
    float* scales = (float*)(ws + o); o += 256;
    float* hbuf = (float*)(ws + o);  o += AL((size_t)NTOT * D128 * 4);
    float* l1out = (float*)(ws + o); o += AL((size_t)NTOT * D128 * 4);
    float* l2out = (float*)(ws + o); o += AL((size_t)NTOT * D128 * 4);
    const size_t R = o;
    const size_t psz = AL((size_t)NBH * NTOT * 4);
    int*   pcnt = (int*)(ws + R);
    float* pdeg = (float*)(ws + R + psz);
    int*   cum  = (int*)(ws + R + 2 * psz);
    float* fush1_m = (float*)(ws + R);
    float* fush1_d = fush1_m + (size_t)NM_ * 256;

    ViewArgs va;
    const int vb_in[4] = {2, 8, 14, 20};
    int nn[4] = {NM_, NM_, ND_, ND_};
    int ee[4] = {EM_, EM_, ED_, ED_};
    int cn = 0, ce = 0;
    for (int v = 0; v < 4; ++v) {
        va.edge[v] = (const int*)d_in[vb_in[v]];
        va.w[v] = (const float*)d_in[vb_in[v] + 1];
        va.n[v] = nn[v];
        va.E[v] = ee[v];
        va.cumn[v] = cn;
        va.cumE[v] = ce;
        va.rpo[v] = cn + v;
        cn += nn[v];
        ce += ee[v];
    }
    va.cumn[4] = cn;
    va.cumE[4] = ce;

    hipMemsetAsync(sums, 0, 8 * 4, stream);

    // ---- CSR build (all views) ----
    hist_b<<<256, 1024, 0, stream>>>(va, pcnt, pdeg);
    csrmeta_b<<<4, 1024, 0, stream>>>(va, pcnt, pdeg, dinv, rowptr, cum);
    fill2_b<<<256, 1024, 0, stream>>>(va, dinv, cum, spair);

    // LDS-staged agg needs >64KB dynamic LDS; fall back deterministically if
    // the attribute can't be set.
    const int ldsM = 16 * 1057 * 4;   // 67648 B
    const int ldsD = 8 * 2177 * 4;    // 69664 B
    bool big =
        hipFuncSetAttribute((const void*)aggL_b<16, 1057>,
                            hipFuncAttributeMaxDynamicSharedMemorySize, 71680) == hipSuccess &&
        hipFuncSetAttribute((const void*)aggL_b<8, 2177>,
                            hipFuncAttributeMaxDynamicSharedMemorySize, 71680) == hipSuccess;

    auto agg_layer = [&](BiasArr bb, float* outb) {
        if (big) {
            // m views: 2 views x (8 cg x 17 chunks) = 272 blocks
            aggL_b<16, 1057><<<272, 256, ldsM, stream>>>(va, spair, rowptr, hbuf, bb, outb,
                                                         0, 136, 17);
            // d views: 2 views x (16 cg x 34 chunks) = 1088 blocks
            aggL_b<8, 2177><<<1088, 256, ldsD, stream>>>(va, spair, rowptr, hbuf, bb, outb,
                                                         2, 544, 34);
        } else {
            agg_b<<<NTOT, 128, 0, stream>>>(va, spair, rowptr, hbuf, bb, outb);
        }
    };

    // ---- layer GEMMs + aggregation ----
    auto feat_gemm = [&](int layer, const float* l1src) {
        GArgs ga;
        ga.nseg = 4;
        ga.l1 = nullptr; ga.l2 = nullptr; ga.scales = nullptr;
        int blk = 0;
        for (int v = 0; v < 4; ++v) {
            GSeg& S = ga.s[v];
            S.A = (layer == 1) ? ((v < 2) ? mirna_x : drug_x)
                               : l1src + (size_t)va.cumn[v] * D128;
            S.W = (const float*)d_in[vb_in[v] + (layer == 1 ? 2 : 4)];
            S.bias = nullptr;
            S.C = hbuf + (size_t)va.cumn[v] * D128;
            S.M = va.n[v]; S.N = 128; S.K = 128;
            S.rowblks = (va.n[v] + 31) / 32;
            S.blk0 = blk; S.relu = 0; S.mode = 0;
            blk += S.rowblks;
        }
        gemm_b<<<blk, 256, 0, stream>>>(ga);
    };
    BiasArr b1, b2;
    for (int v = 0; v < 4; ++v) {
        b1.b[v] = (const float*)d_in[vb_in[v] + 3];
        b2.b[v] = (const float*)d_in[vb_in[v] + 5];
    }

    feat_gemm(1, nullptr);
    agg_layer(b1, l1out);
    feat_gemm(2, l1out);
    agg_layer(b2, l2out);

    // ---- channel sums -> attention scales ----
    SumArgs sa;
    sa.p[0] = l1out;                      sa.p[1] = l2out;
    sa.p[2] = l1out + (size_t)1043 * 128; sa.p[3] = l2out + (size_t)1043 * 128;
    sa.p[4] = l1out + (size_t)2086 * 128; sa.p[5] = l2out + (size_t)2086 * 128;
    sa.p[6] = l1out + (size_t)4252 * 128; sa.p[7] = l2out + (size_t)4252 * 128;
    sa.cnt[0] = sa.cnt[1] = sa.cnt[2] = sa.cnt[3] = NM_ * D128;
    sa.cnt[4] = sa.cnt[5] = sa.cnt[6] = sa.cnt[7] = ND_ * D128;
    sum8_kernel<<<dim3(16, 8), 256, 0, stream>>>(sa, sums);
    att_kernel<<<1, 64, 0, stream>>>(sums,
        (const float*)d_in[26], (const float*)d_in[27], (const float*)d_in[28], (const float*)d_in[29],
        (const float*)d_in[30], (const float*)d_in[31], (const float*)d_in[32], (const float*)d_in[33],
        scales);

    // ---- fusion GEMM-1 with concat fused into the A-loader ----
    {
        GArgs ga;
        ga.nseg = 2;
        ga.l1 = l1out; ga.l2 = l2out; ga.scales = scales;
        ga.s[0] = {nullptr, (const float*)d_in[34], (const float*)d_in[35], fush1_m,
                   NM_, 256, 512, 33, 0, 1, 1};
        ga.s[1] = {nullptr, (const float*)d_in[38], (const float*)d_in[39], fush1_d,
                   ND_, 256, 256, 68, 66, 1, 2};
        gemm_b<<<66 + 136, 256, 0, stream>>>(ga);
    }
    // ---- fusion GEMM-2 (plain) ----
    {
        GArgs ga;
        ga.nseg = 2;
        ga.l1 = nullptr; ga.l2 = nullptr; ga.scales = nullptr;
        ga.s[0] = {fush1_m, (const float*)d_in[36], (const float*)d_in[37], out,
                   NM_, 128, 256, 33, 0, 1, 0};
        ga.s[1] = {fush1_d, (const float*)d_in[40], (const float*)d_in[41],
                   out + (size_t)NM_ * D128, ND_, 128, 256, 68, 33, 1, 0};
        gemm_b<<<33 + 68, 256, 0, stream>>>(ga);
    }
}

// Round 9
// 287.108 us; speedup vs baseline: 2.3598x; 2.3598x over previous
//
#include <hip/hip_runtime.h>
#include <math.h>

#define D128 128
#define NM_ 1043
#define ND_ 2166
#define EM_ 300000
#define ED_ 600000
#define NBH 64              // chunks per view (hist + fill)
#define NMAX 2176
#define NTOT 6418           // 2*1043 + 2*2166
#define ETOT 1800000

struct ViewArgs {
    const int* edge[4];
    const float* w[4];
    int n[4], E[4];
    int cumn[5];
    int cumE[5];
    int rpo[4];
};

struct BiasArr { const float* b[4]; };

// ---------------------------------------------------------------------------
// unified multi-segment GEMM core: C[M,N] = A[M,K] @ W[N,K]^T (+bias, relu)
// mode 0: plain A; mode 1: miRNA concat-on-the-fly; mode 2: drug concat.
// ---------------------------------------------------------------------------
struct GSeg {
    const float* A;
    const float* W;
    const float* bias;
    float* C;
    int M, N, K, rowblks, blk0, relu, mode;
};
struct GArgs {
    GSeg s[4];
    int nseg;
    const float* l1;
    const float* l2;
    const float* scales;
};

__device__ __forceinline__ void gemm_core(const GArgs& ga, int bid, int tid,
                                          float* xs, float* wsm) {
    int si = 0;
    while (si + 1 < ga.nseg && bid >= ga.s[si + 1].blk0) ++si;
    const GSeg S = ga.s[si];
    const int lb = bid - S.blk0;
    const int rb = lb % S.rowblks, cb = lb / S.rowblks;
    const int row0 = rb * 32, col0 = cb * 128;
    const int r0 = (tid >> 5) << 2;
    const int c0 = tid & 31;
    const int csw = (c0 & 7) << 2;
    float acc[4][4] = {};
    for (int kc = 0; kc < S.K; kc += 64) {
#pragma unroll
        for (int it = 0; it < 2; ++it) {
            int idx = tid + it * 256;
            int r = idx >> 4, k4 = (idx & 15) << 2;
            int gr = row0 + r;
            if (gr > S.M - 1) gr = S.M - 1;
            float4 v;
            if (S.mode == 0) {
                v = *(const float4*)(S.A + (size_t)gr * S.K + kc + k4);
            } else {
                int kk = kc + k4;
                int c = kk >> 7, j = kk & 127;
                if (S.mode == 1) {
                    const float* base = (c == 0) ? ga.l1 : (c == 1) ? ga.l2
                                       : (c == 2) ? ga.l1 + 133504 : ga.l2 + 133504;
                    v = *(const float4*)(base + (size_t)gr * 128 + j);
                    float s = ga.scales[c];
                    v.x *= s; v.y *= s; v.z *= s; v.w *= s;
                } else {
                    const float* bp = c ? ga.l2 : ga.l1;
                    float4 va4 = *(const float4*)(bp + 267008 + (size_t)gr * 128 + j);
                    float4 vb4 = *(const float4*)(bp + 544256 + (size_t)gr * 128 + j);
                    float s = ga.scales[4 + c];
                    v.x = s * (va4.x + vb4.x);
                    v.y = s * (va4.y + vb4.y);
                    v.z = s * (va4.z + vb4.z);
                    v.w = s * (va4.w + vb4.w);
                }
            }
            *(float4*)(xs + r * 64 + k4) = v;
        }
#pragma unroll
        for (int it = 0; it < 8; ++it) {
            int idx = tid + it * 256;
            int c = idx >> 4, k4 = (idx & 15) << 2;
            *(float4*)(wsm + c * 64 + (k4 ^ ((c & 7) << 2))) =
                *(const float4*)(S.W + (size_t)(col0 + c) * S.K + kc + k4);
        }
        __syncthreads();
#pragma unroll
        for (int k4 = 0; k4 < 64; k4 += 4) {
            float4 a0 = *(const float4*)(xs + (r0 + 0) * 64 + k4);
            float4 a1 = *(const float4*)(xs + (r0 + 1) * 64 + k4);
            float4 a2 = *(const float4*)(xs + (r0 + 2) * 64 + k4);
            float4 a3 = *(const float4*)(xs + (r0 + 3) * 64 + k4);
            const int sk = k4 ^ csw;
            float4 w0 = *(const float4*)(wsm + (c0 + 0) * 64 + sk);
            float4 w1 = *(const float4*)(wsm + (c0 + 32) * 64 + sk);
            float4 w2 = *(const float4*)(wsm + (c0 + 64) * 64 + sk);
            float4 w3 = *(const float4*)(wsm + (c0 + 96) * 64 + sk);
#define FMA4(i, av)                                                   \
            acc[i][0] = fmaf(av.x, w0.x, acc[i][0]); acc[i][0] = fmaf(av.y, w0.y, acc[i][0]); \
            acc[i][0] = fmaf(av.z, w0.z, acc[i][0]); acc[i][0] = fmaf(av.w, w0.w, acc[i][0]); \
            acc[i][1] = fmaf(av.x, w1.x, acc[i][1]); acc[i][1] = fmaf(av.y, w1.y, acc[i][1]); \
            acc[i][1] = fmaf(av.z, w1.z, acc[i][1]); acc[i][1] = fmaf(av.w, w1.w, acc[i][1]); \
            acc[i][2] = fmaf(av.x, w2.x, acc[i][2]); acc[i][2] = fmaf(av.y, w2.y, acc[i][2]); \
            acc[i][2] = fmaf(av.z, w2.z, acc[i][2]); acc[i][2] = fmaf(av.w, w2.w, acc[i][2]); \
            acc[i][3] = fmaf(av.x, w3.x, acc[i][3]); acc[i][3] = fmaf(av.y, w3.y, acc[i][3]); \
            acc[i][3] = fmaf(av.z, w3.z, acc[i][3]); acc[i][3] = fmaf(av.w, w3.w, acc[i][3]);
            FMA4(0, a0) FMA4(1, a1) FMA4(2, a2) FMA4(3, a3)
#undef FMA4
        }
        __syncthreads();
    }
#pragma unroll
    for (int i = 0; i < 4; ++i) {
        int gr = row0 + r0 + i;
        if (gr < S.M) {
#pragma unroll
            for (int j = 0; j < 4; ++j) {
                int gc = col0 + c0 + 32 * j;
                float v = acc[i][j];
                if (S.bias) v += S.bias[gc];
                if (S.relu) v = fmaxf(v, 0.f);
                S.C[(size_t)gr * S.N + gc] = v;
            }
        }
    }
}

__global__ __launch_bounds__(256) void gemm_b(GArgs ga) {
    __shared__ __align__(16) float smem[10240];   // 40 KB: xs(2048) + wsm(8192)
    gemm_core(ga, blockIdx.x, threadIdx.x, smem, smem + 2048);
}

// ---------------------------------------------------------------------------
// merged: blocks [0,256) = per-chunk privatized histograms (LDS atomics);
//         blocks [256, 256+gemmblks) = layer-1 feature GEMM (independent work
//         overlapped in one launch instead of serializing on the stream).
// ---------------------------------------------------------------------------
__global__ __launch_bounds__(256) void histgemm_b(ViewArgs va, int* __restrict__ pcnt,
                                                  float* __restrict__ pdeg, GArgs ga) {
    __shared__ __align__(16) float smem[10240];
    if (blockIdx.x < 256) {
        int* lc = (int*)smem;
        float* ld = smem + NMAX;
        const int view = blockIdx.x >> 6, vb = blockIdx.x & 63;
        const int n = va.n[view], E = va.E[view];
        const int* edge = va.edge[view];
        const float* w = va.w[view];
        for (int i = threadIdx.x; i < n; i += 256) { lc[i] = 0; ld[i] = 0.f; }
        __syncthreads();
        const int per = (E + NBH - 1) / NBH;
        const int b = vb * per, e = min(E, b + per);
        for (int i = b + threadIdx.x; i < e; i += 256) {
            int dst = edge[E + i];
            atomicAdd(&lc[dst], 1);
            atomicAdd(&ld[dst], w[i]);
        }
        __syncthreads();
        int* pc = pcnt + (size_t)NBH * va.cumn[view] + (size_t)vb * n;
        float* pd = pdeg + (size_t)NBH * va.cumn[view] + (size_t)vb * n;
        for (int i = threadIdx.x; i < n; i += 256) { pc[i] = lc[i]; pd[i] = ld[i]; }
    } else {
        gemm_core(ga, blockIdx.x - 256, threadIdx.x, smem, smem + 2048);
    }
}

// ---------------------------------------------------------------------------
// merged colred + scan + cum: one block per view
// ---------------------------------------------------------------------------
__global__ __launch_bounds__(1024) void csrmeta_b(ViewArgs va, const int* __restrict__ pcnt,
                                                  const float* __restrict__ pdeg,
                                                  float* __restrict__ dinv,
                                                  int* __restrict__ rowptr,
                                                  int* __restrict__ cum) {
    __shared__ int lcnt[NMAX];
    __shared__ int wsum[16];
    const int view = blockIdx.x;
    const int n = va.n[view];
    const int* pc = pcnt + (size_t)NBH * va.cumn[view];
    const float* pd = pdeg + (size_t)NBH * va.cumn[view];
    int* rp = rowptr + va.rpo[view];
    float* dv = dinv + va.cumn[view];
    int* cm = cum + (size_t)NBH * va.cumn[view];
    const int tid = threadIdx.x;
    for (int i = tid; i < n; i += 1024) {
        int c = 0;
        float dg = 0.f;
        for (int b = 0; b < NBH; ++b) {
            c += pc[(size_t)b * n + i];
            dg += pd[(size_t)b * n + i];
        }
        lcnt[i] = c;
        dv[i] = dg > 0.f ? 1.0f / sqrtf(dg) : 0.f;
    }
    __syncthreads();
    const int per = (n + 1023) / 1024;
    const int b0 = min(n, tid * per), e0 = min(n, b0 + per);
    int s = 0;
    for (int i = b0; i < e0; ++i) s += lcnt[i];
    const int lane = tid & 63, wid = tid >> 6;
    int sc = s;
    for (int off = 1; off < 64; off <<= 1) {
        int t = __shfl_up(sc, off);
        if (lane >= off) sc += t;
    }
    if (lane == 63) wsum[wid] = sc;
    __syncthreads();
    int wbase = 0;
    for (int wv = 0; wv < wid; ++wv) wbase += wsum[wv];
    int run = wbase + sc - s;
    if (tid == 0) rp[0] = 0;
    for (int i = b0; i < e0; ++i) {
        int c = lcnt[i];
        lcnt[i] = run;
        run += c;
        rp[i + 1] = run;
    }
    __syncthreads();
    for (int i = tid; i < n; i += 1024) {
        int r = lcnt[i];
        for (int b = 0; b < NBH; ++b) {
            cm[(size_t)b * n + i] = r;
            r += pc[(size_t)b * n + i];
        }
    }
}

// CSR build pass 2: place (src, norm) pairs; int2 writes
__global__ __launch_bounds__(1024) void fill2_b(ViewArgs va, const float* __restrict__ dinv,
                                                const int* __restrict__ cum,
                                                int2* __restrict__ spair) {
    __shared__ int lc[NMAX];
    const int view = blockIdx.x >> 6, vb = blockIdx.x & 63;
    const int n = va.n[view], E = va.E[view];
    const int* edge = va.edge[view];
    const float* w = va.w[view];
    const int* cm = cum + (size_t)NBH * va.cumn[view] + (size_t)vb * n;
    const float* dv = dinv + va.cumn[view];
    int2* sp = spair + va.cumE[view];
    for (int i = threadIdx.x; i < n; i += 1024) lc[i] = cm[i];
    __syncthreads();
    const int per = (E + NBH - 1) / NBH;
    const int b = vb * per, e = min(E, b + per);
    for (int i = b + threadIdx.x; i < e; i += 1024) {
        int src = edge[i];
        int dst = edge[E + i];
        int pos = atomicAdd(&lc[dst], 1);
        float nrm = dv[src] * w[i] * dv[dst];
        sp[pos] = make_int2(src, __float_as_int(nrm));
    }
}

// ---------------------------------------------------------------------------
// fused edge aggregation + bias + relu (r5-proven shape): one block (128 thr)
// per node, L2 gathers, unroll 4 — plus bijective XCD swizzle (the one
// variable r6 confounded with its shape change).
// ---------------------------------------------------------------------------
__global__ __launch_bounds__(128) void agg_b(ViewArgs va, const int2* __restrict__ spair,
                                             const int* __restrict__ rowptr,
                                             const float* __restrict__ h, BiasArr ba,
                                             float* __restrict__ outbuf) {
    // bijective XCD swizzle: NTOT = 8*802 + 2
    const int xcd = blockIdx.x & 7, k = blockIdx.x >> 3;
    const int nf = (xcd < 2 ? xcd * 803 : 2 * 803 + (xcd - 2) * 802) + k;
    int view = 0;
    while (view < 3 && nf >= va.cumn[view + 1]) ++view;
    const int ln = nf - va.cumn[view];
    const int* rp = rowptr + va.rpo[view];
    const int beg = rp[ln], end = rp[ln + 1];
    const int2* sp = spair + va.cumE[view];
    const float* hb = h + (size_t)va.cumn[view] * D128;
    const int tid = threadIdx.x;
    float a0 = 0.f, a1 = 0.f, a2 = 0.f, a3 = 0.f;
    int i = beg;
    for (; i + 4 <= end; i += 4) {
        int2 p0 = sp[i], p1 = sp[i + 1], p2 = sp[i + 2], p3 = sp[i + 3];
        a0 = fmaf(__int_as_float(p0.y), hb[(size_t)p0.x * D128 + tid], a0);
        a1 = fmaf(__int_as_float(p1.y), hb[(size_t)p1.x * D128 + tid], a1);
        a2 = fmaf(__int_as_float(p2.y), hb[(size_t)p2.x * D128 + tid], a2);
        a3 = fmaf(__int_as_float(p3.y), hb[(size_t)p3.x * D128 + tid], a3);
    }
    for (; i < end; ++i)
        a0 = fmaf(__int_as_float(sp[i].y), hb[(size_t)sp[i].x * D128 + tid], a0);
    float v = (a0 + a1) + (a2 + a3);
    outbuf[(size_t)nf * D128 + tid] = fmaxf(v + ba.b[view][tid], 0.f);
}

// ---------------------------------------------------------------------------
// channel sums + attention scales
// ---------------------------------------------------------------------------
struct SumArgs {
    const float* p[8];
    int cnt[8];
};

__global__ __launch_bounds__(256) void sum8_kernel(SumArgs args, float* __restrict__ sums) {
    __shared__ float red[256];
    const int ch = blockIdx.y;
    const float* x = args.p[ch];
    const int count = args.cnt[ch];
    float s = 0.f;
    for (int i = blockIdx.x * 256 + threadIdx.x; i < count; i += gridDim.x * 256) s += x[i];
    red[threadIdx.x] = s;
    __syncthreads();
    for (int off = 128; off > 0; off >>= 1) {
        if (threadIdx.x < off) red[threadIdx.x] += red[threadIdx.x + off];
        __syncthreads();
    }
    if (threadIdx.x == 0) atomicAdd(&sums[ch], red[0]);
}

__global__ void att_kernel(const float* __restrict__ sums,
                           const float* __restrict__ mW1, const float* __restrict__ mb1,
                           const float* __restrict__ mW2, const float* __restrict__ mb2,
                           const float* __restrict__ dW1, const float* __restrict__ db1,
                           const float* __restrict__ dW2, const float* __restrict__ db2,
                           float* __restrict__ scales) {
    if (threadIdx.x != 0 || blockIdx.x != 0) return;
    float mean[4], a[4];
    const float invM = 1.0f / (128.f * (float)NM_);
    for (int c = 0; c < 4; ++c) mean[c] = sums[c] * invM;
    for (int i = 0; i < 4; ++i) {
        float v = mb1[i];
        for (int j = 0; j < 4; ++j) v += mW1[i * 4 + j] * mean[j];
        a[i] = fmaxf(v, 0.f);
    }
    for (int c = 0; c < 4; ++c) {
        float v = mb2[c];
        for (int j = 0; j < 4; ++j) v += mW2[c * 4 + j] * a[j];
        scales[c] = 1.f / (1.f + expf(-v));
    }
    const float invD = 1.0f / (128.f * (float)ND_);
    float md[2] = {(sums[4] + sums[6]) * invD, (sums[5] + sums[7]) * invD};
    float ad[2];
    for (int i = 0; i < 2; ++i) {
        float v = db1[i];
        for (int j = 0; j < 2; ++j) v += dW1[i * 2 + j] * md[j];
        ad[i] = fmaxf(v, 0.f);
    }
    for (int c = 0; c < 2; ++c) {
        float v = db2[c];
        for (int j = 0; j < 2; ++j) v += dW2[c * 2 + j] * ad[j];
        scales[4 + c] = 1.f / (1.f + expf(-v));
    }
}

// ---------------------------------------------------------------------------
extern "C" void kernel_launch(void* const* d_in, const int* in_sizes, int n_in,
                              void* d_out, int out_size, void* d_ws, size_t ws_size,
                              hipStream_t stream) {
    const float* mirna_x = (const float*)d_in[0];
    const float* drug_x  = (const float*)d_in[1];
    float* out = (float*)d_out;
    (void)in_sizes; (void)n_in; (void)out_size; (void)ws_size;

    char* ws = (char*)d_ws;
    auto AL = [](size_t x) { return (x + 255) & ~(size_t)255; };
    size_t o = 0;
    int2* spair = (int2*)(ws + o);   o += AL((size_t)ETOT * 8);
    int* rowptr = (int*)(ws + o);    o += AL((size_t)(NTOT + 4) * 4);
    float* dinv = (float*)(ws + o);  o += AL((size_t)NTOT * 4);
    float* sums = (float*)(ws + o);  o += 256;
    float* scales = (float*)(ws + o); o += 256;
    float* hbuf = (float*)(ws + o);  o += AL((size_t)NTOT * D128 * 4);
    float* l1out = (float*)(ws + o); o += AL((size_t)NTOT * D128 * 4);
    float* l2out = (float*)(ws + o); o += AL((size_t)NTOT * D128 * 4);
    const size_t R = o;
    const size_t psz = AL((size_t)NBH * NTOT * 4);
    int*   pcnt = (int*)(ws + R);
    float* pdeg = (float*)(ws + R + psz);
    int*   cum  = (int*)(ws + R + 2 * psz);
    float* fush1_m = (float*)(ws + R);
    float* fush1_d = fush1_m + (size_t)NM_ * 256;

    ViewArgs va;
    const int vb_in[4] = {2, 8, 14, 20};
    int nn[4] = {NM_, NM_, ND_, ND_};
    int ee[4] = {EM_, EM_, ED_, ED_};
    int cn = 0, ce = 0;
    for (int v = 0; v < 4; ++v) {
        va.edge[v] = (const int*)d_in[vb_in[v]];
        va.w[v] = (const float*)d_in[vb_in[v] + 1];
        va.n[v] = nn[v];
        va.E[v] = ee[v];
        va.cumn[v] = cn;
        va.cumE[v] = ce;
        va.rpo[v] = cn + v;
        cn += nn[v];
        ce += ee[v];
    }
    va.cumn[4] = cn;
    va.cumE[4] = ce;

    hipMemsetAsync(sums, 0, 8 * 4, stream);

    BiasArr b1, b2;
    for (int v = 0; v < 4; ++v) {
        b1.b[v] = (const float*)d_in[vb_in[v] + 3];
        b2.b[v] = (const float*)d_in[vb_in[v] + 5];
    }

    auto make_feat = [&](int layer, const float* l1src) {
        GArgs ga;
        ga.nseg = 4;
        ga.l1 = nullptr; ga.l2 = nullptr; ga.scales = nullptr;
        int blk = 0;
        for (int v = 0; v < 4; ++v) {
            GSeg& S = ga.s[v];
            S.A = (layer == 1) ? ((v < 2) ? mirna_x : drug_x)
                               : l1src + (size_t)va.cumn[v] * D128;
            S.W = (const float*)d_in[vb_in[v] + (layer == 1 ? 2 : 4)];
            S.bias = nullptr;
            S.C = hbuf + (size_t)va.cumn[v] * D128;
            S.M = va.n[v]; S.N = 128; S.K = 128;
            S.rowblks = (va.n[v] + 31) / 32;
            S.blk0 = blk; S.relu = 0; S.mode = 0;
            blk += S.rowblks;
        }
        return ga;   // blk == 202
    };

    // ---- hist + layer-1 feature GEMM in ONE launch (independent work) ----
    {
        GArgs g1 = make_feat(1, nullptr);
        histgemm_b<<<256 + 202, 256, 0, stream>>>(va, pcnt, pdeg, g1);
    }
    csrmeta_b<<<4, 1024, 0, stream>>>(va, pcnt, pdeg, dinv, rowptr, cum);
    fill2_b<<<256, 1024, 0, stream>>>(va, dinv, cum, spair);

    // ---- layer 1 aggregation ----
    agg_b<<<NTOT, 128, 0, stream>>>(va, spair, rowptr, hbuf, b1, l1out);
    // ---- layer 2 GEMM + aggregation ----
    {
        GArgs g2 = make_feat(2, l1out);
        gemm_b<<<202, 256, 0, stream>>>(g2);
    }
    agg_b<<<NTOT, 128, 0, stream>>>(va, spair, rowptr, hbuf, b2, l2out);

    // ---- channel sums -> attention scales ----
    SumArgs sa;
    sa.p[0] = l1out;                      sa.p[1] = l2out;
    sa.p[2] = l1out + (size_t)1043 * 128; sa.p[3] = l2out + (size_t)1043 * 128;
    sa.p[4] = l1out + (size_t)2086 * 128; sa.p[5] = l2out + (size_t)2086 * 128;
    sa.p[6] = l1out + (size_t)4252 * 128; sa.p[7] = l2out + (size_t)4252 * 128;
    sa.cnt[0] = sa.cnt[1] = sa.cnt[2] = sa.cnt[3] = NM_ * D128;
    sa.cnt[4] = sa.cnt[5] = sa.cnt[6] = sa.cnt[7] = ND_ * D128;
    sum8_kernel<<<dim3(16, 8), 256, 0, stream>>>(sa, sums);
    att_kernel<<<1, 64, 0, stream>>>(sums,
        (const float*)d_in[26], (const float*)d_in[27], (const float*)d_in[28], (const float*)d_in[29],
        (const float*)d_in[30], (const float*)d_in[31], (const float*)d_in[32], (const float*)d_in[33],
        scales);

    // ---- fusion GEMM-1 with concat fused into the A-loader ----
    {
        GArgs ga;
        ga.nseg = 2;
        ga.l1 = l1out; ga.l2 = l2out; ga.scales = scales;
        ga.s[0] = {nullptr, (const float*)d_in[34], (const float*)d_in[35], fush1_m,
                   NM_, 256, 512, 33, 0, 1, 1};
        ga.s[1] = {nullptr, (const float*)d_in[38], (const float*)d_in[39], fush1_d,
                   ND_, 256, 256, 68, 66, 1, 2};
        gemm_b<<<66 + 136, 256, 0, stream>>>(ga);
    }
    // ---- fusion GEMM-2 (plain) ----
    {
        GArgs ga;
        ga.nseg = 2;
        ga.l1 = nullptr; ga.l2 = nullptr; ga.scales = nullptr;
        ga.s[0] = {fush1_m, (const float*)d_in[36], (const float*)d_in[37], out,
                   NM_, 128, 256, 33, 0, 1, 0};
        ga.s[1] = {fush1_d, (const float*)d_in[40], (const float*)d_in[41],
                   out + (size_t)NM_ * D128, ND_, 128, 256, 68, 33, 1, 0};
        gemm_b<<<33 + 68, 256, 0, stream>>>(ga);
    }
}

// Round 12
// 271.956 us; speedup vs baseline: 2.4913x; 1.0557x over previous
//
#include <hip/hip_runtime.h>
#include <math.h>

#define D128 128
#define NM_ 1043
#define ND_ 2166
#define EM_ 300000
#define ED_ 600000
#define NBH 64              // chunks per view (hist + fill)
#define NMAX 2176
#define NTOT 6418           // 2*1043 + 2*2166
#define ETOT 1800000

struct ViewArgs {
    const int* edge[4];
    const float* w[4];
    int n[4], E[4];
    int cumn[5];
    int cumE[5];
    int rpo[4];
};

struct BiasArr { const float* b[4]; };

// ---------------------------------------------------------------------------
// CSR build, pass 1: per-chunk privatized histograms (LDS atomics only)
// ---------------------------------------------------------------------------
__global__ __launch_bounds__(1024) void hist_b(ViewArgs va, int* __restrict__ pcnt,
                                               float* __restrict__ pdeg) {
    __shared__ int lc[NMAX];
    __shared__ float ld[NMAX];
    const int view = blockIdx.x >> 6, vb = blockIdx.x & 63;
    const int n = va.n[view], E = va.E[view];
    const int* edge = va.edge[view];
    const float* w = va.w[view];
    for (int i = threadIdx.x; i < n; i += 1024) { lc[i] = 0; ld[i] = 0.f; }
    __syncthreads();
    const int per = (E + NBH - 1) / NBH;
    const int b = vb * per, e = min(E, b + per);
    for (int i = b + threadIdx.x; i < e; i += 1024) {
        int dst = edge[E + i];
        atomicAdd(&lc[dst], 1);
        atomicAdd(&ld[dst], w[i]);
    }
    __syncthreads();
    int* pc = pcnt + (size_t)NBH * va.cumn[view] + (size_t)vb * n;
    float* pd = pdeg + (size_t)NBH * va.cumn[view] + (size_t)vb * n;
    for (int i = threadIdx.x; i < n; i += 1024) { pc[i] = lc[i]; pd[i] = ld[i]; }
}

__global__ void colred_b(ViewArgs va, const int* __restrict__ pcnt,
                         const float* __restrict__ pdeg, int* __restrict__ cnt,
                         float* __restrict__ dinv) {
    int i = blockIdx.x * 256 + threadIdx.x;
    if (i >= NTOT) return;
    int view = 0;
    while (view < 3 && i >= va.cumn[view + 1]) ++view;
    const int il = i - va.cumn[view], n = va.n[view];
    const int* pc = pcnt + (size_t)NBH * va.cumn[view];
    const float* pd = pdeg + (size_t)NBH * va.cumn[view];
    int c = 0;
    float dg = 0.f;
    for (int b = 0; b < NBH; ++b) {
        c += pc[(size_t)b * n + il];
        dg += pd[(size_t)b * n + il];
    }
    cnt[i] = c;
    dinv[i] = dg > 0.f ? 1.0f / sqrtf(dg) : 0.f;
}

// lean per-view exclusive scan: serial local sums + shfl wave scan
__global__ void scan_b(ViewArgs va, const int* __restrict__ cnt, int* __restrict__ rowptr) {
    __shared__ int wsum[4];
    const int view = blockIdx.x;
    const int n = va.n[view];
    const int* c = cnt + va.cumn[view];
    int* rp = rowptr + va.rpo[view];
    const int tid = threadIdx.x;
    const int per = (n + 255) / 256;
    const int b0 = tid * per, e0 = min(n, b0 + per);
    int s = 0;
    for (int i = b0; i < e0; ++i) s += c[i];
    const int lane = tid & 63, wid = tid >> 6;
    int sc = s;
    for (int off = 1; off < 64; off <<= 1) {
        int t = __shfl_up(sc, off);
        if (lane >= off) sc += t;
    }
    if (lane == 63) wsum[wid] = sc;
    __syncthreads();
    int wbase = 0;
    for (int wv = 0; wv < wid; ++wv) wbase += wsum[wv];
    int run = wbase + sc - s;       // exclusive base for this thread's range
    if (tid == 0) rp[0] = 0;
    for (int i = b0; i < e0; ++i) {
        run += c[i];
        rp[i + 1] = run;
    }
}

// per-(chunk,bin) bases: cum[c][i] = rowptr[i] + sum_{c'<c} pcnt[c'][i]
__global__ void cum_b(ViewArgs va, const int* __restrict__ pcnt,
                      const int* __restrict__ rowptr, int* __restrict__ cum) {
    int i = blockIdx.x * 256 + threadIdx.x;
    if (i >= NTOT) return;
    int view = 0;
    while (view < 3 && i >= va.cumn[view + 1]) ++view;
    const int il = i - va.cumn[view], n = va.n[view];
    const int* pc = pcnt + (size_t)NBH * va.cumn[view];
    int* cm = cum + (size_t)NBH * va.cumn[view];
    int run = rowptr[va.rpo[view] + il];
    for (int b = 0; b < NBH; ++b) {
        cm[(size_t)b * n + il] = run;
        run += pc[(size_t)b * n + il];
    }
}

// CSR build pass 2: place (src, norm) pairs; int2 writes
__global__ __launch_bounds__(1024) void fill2_b(ViewArgs va, const float* __restrict__ dinv,
                                                const int* __restrict__ cum,
                                                int2* __restrict__ spair) {
    __shared__ int lc[NMAX];
    const int view = blockIdx.x >> 6, vb = blockIdx.x & 63;
    const int n = va.n[view], E = va.E[view];
    const int* edge = va.edge[view];
    const float* w = va.w[view];
    const int* cm = cum + (size_t)NBH * va.cumn[view] + (size_t)vb * n;
    const float* dv = dinv + va.cumn[view];
    int2* sp = spair + va.cumE[view];
    for (int i = threadIdx.x; i < n; i += 1024) lc[i] = cm[i];
    __syncthreads();
    const int per = (E + NBH - 1) / NBH;
    const int b = vb * per, e = min(E, b + per);
    for (int i = b + threadIdx.x; i < e; i += 1024) {
        int src = edge[i];
        int dst = edge[E + i];
        int pos = atomicAdd(&lc[dst], 1);
        float nrm = dv[src] * w[i] * dv[dst];
        sp[pos] = make_int2(src, __float_as_int(nrm));
    }
}

// ---------------------------------------------------------------------------
// fused edge aggregation + bias + relu: one block (128 thr) per node with
// bijective XCD swizzle (r9-measured: 60.5us, FETCH 18.9MB vs 62.0/27.5 plain)
// ---------------------------------------------------------------------------
__global__ __launch_bounds__(128) void agg_b(ViewArgs va, const int2* __restrict__ spair,
                                             const int* __restrict__ rowptr,
                                             const float* __restrict__ h, BiasArr ba,
                                             float* __restrict__ outbuf) {
    // bijective XCD swizzle: NTOT = 8*802 + 2
    const int xcd = blockIdx.x & 7, k = blockIdx.x >> 3;
    const int nf = (xcd < 2 ? xcd * 803 : 2 * 803 + (xcd - 2) * 802) + k;
    int view = 0;
    while (view < 3 && nf >= va.cumn[view + 1]) ++view;
    const int ln = nf - va.cumn[view];
    const int* rp = rowptr + va.rpo[view];
    const int beg = rp[ln], end = rp[ln + 1];
    const int2* sp = spair + va.cumE[view];
    const float* hb = h + (size_t)va.cumn[view] * D128;
    const int tid = threadIdx.x;
    float a0 = 0.f, a1 = 0.f, a2 = 0.f, a3 = 0.f;
    int i = beg;
    for (; i + 4 <= end; i += 4) {
        int2 p0 = sp[i], p1 = sp[i + 1], p2 = sp[i + 2], p3 = sp[i + 3];
        a0 = fmaf(__int_as_float(p0.y), hb[(size_t)p0.x * D128 + tid], a0);
        a1 = fmaf(__int_as_float(p1.y), hb[(size_t)p1.x * D128 + tid], a1);
        a2 = fmaf(__int_as_float(p2.y), hb[(size_t)p2.x * D128 + tid], a2);
        a3 = fmaf(__int_as_float(p3.y), hb[(size_t)p3.x * D128 + tid], a3);
    }
    for (; i < end; ++i)
        a0 = fmaf(__int_as_float(sp[i].y), hb[(size_t)sp[i].x * D128 + tid], a0);
    float v = (a0 + a1) + (a2 + a3);
    outbuf[(size_t)nf * D128 + tid] = fmaxf(v + ba.b[view][tid], 0.f);
}

// ---------------------------------------------------------------------------
// unified multi-segment GEMM: C[M,N] = A[M,K] @ W[N,K]^T (+bias, relu)
// ---------------------------------------------------------------------------
struct GSeg {
    const float* A;
    const float* W;
    const float* bias;
    float* C;
    int M, N, K, rowblks, blk0, relu;
};
struct GArgs { GSeg s[4]; int nseg; };

__global__ __launch_bounds__(256) void gemm_b(GArgs ga) {
    __shared__ float xs[32 * 64];
    __shared__ float wsm[128 * 64];
    int si = 0;
    while (si + 1 < ga.nseg && (int)blockIdx.x >= ga.s[si + 1].blk0) ++si;
    const GSeg S = ga.s[si];
    const int lb = blockIdx.x - S.blk0;
    const int rb = lb % S.rowblks, cb = lb / S.rowblks;
    const int row0 = rb * 32, col0 = cb * 128;
    const int tid = threadIdx.x;
    const int r0 = (tid >> 5) << 2;
    const int c0 = tid & 31;
    const int csw = (c0 & 7) << 2;
    float acc[4][4] = {};
    for (int kc = 0; kc < S.K; kc += 64) {
#pragma unroll
        for (int it = 0; it < 2; ++it) {
            int idx = tid + it * 256;
            int r = idx >> 4, k4 = (idx & 15) << 2;
            int gr = row0 + r;
            if (gr > S.M - 1) gr = S.M - 1;
            *(float4*)(xs + r * 64 + k4) =
                *(const float4*)(S.A + (size_t)gr * S.K + kc + k4);
        }
#pragma unroll
        for (int it = 0; it < 8; ++it) {
            int idx = tid + it * 256;
            int c = idx >> 4, k4 = (idx & 15) << 2;
            *(float4*)(wsm + c * 64 + (k4 ^ ((c & 7) << 2))) =
                *(const float4*)(S.W + (size_t)(col0 + c) * S.K + kc + k4);
        }
        __syncthreads();
#pragma unroll
        for (int k4 = 0; k4 < 64; k4 += 4) {
            float4 a0 = *(const float4*)(xs + (r0 + 0) * 64 + k4);
            float4 a1 = *(const float4*)(xs + (r0 + 1) * 64 + k4);
            float4 a2 = *(const float4*)(xs + (r0 + 2) * 64 + k4);
            float4 a3 = *(const float4*)(xs + (r0 + 3) * 64 + k4);
            const int sk = k4 ^ csw;
            float4 w0 = *(const float4*)(wsm + (c0 + 0) * 64 + sk);
            float4 w1 = *(const float4*)(wsm + (c0 + 32) * 64 + sk);
            float4 w2 = *(const float4*)(wsm + (c0 + 64) * 64 + sk);
            float4 w3 = *(const float4*)(wsm + (c0 + 96) * 64 + sk);
#define FMA4(i, av)                                                   \
            acc[i][0] = fmaf(av.x, w0.x, acc[i][0]); acc[i][0] = fmaf(av.y, w0.y, acc[i][0]); \
            acc[i][0] = fmaf(av.z, w0.z, acc[i][0]); acc[i][0] = fmaf(av.w, w0.w, acc[i][0]); \
            acc[i][1] = fmaf(av.x, w1.x, acc[i][1]); acc[i][1] = fmaf(av.y, w1.y, acc[i][1]); \
            acc[i][1] = fmaf(av.z, w1.z, acc[i][1]); acc[i][1] = fmaf(av.w, w1.w, acc[i][1]); \
            acc[i][2] = fmaf(av.x, w2.x, acc[i][2]); acc[i][2] = fmaf(av.y, w2.y, acc[i][2]); \
            acc[i][2] = fmaf(av.z, w2.z, acc[i][2]); acc[i][2] = fmaf(av.w, w2.w, acc[i][2]); \
            acc[i][3] = fmaf(av.x, w3.x, acc[i][3]); acc[i][3] = fmaf(av.y, w3.y, acc[i][3]); \
            acc[i][3] = fmaf(av.z, w3.z, acc[i][3]); acc[i][3] = fmaf(av.w, w3.w, acc[i][3]);
            FMA4(0, a0) FMA4(1, a1) FMA4(2, a2) FMA4(3, a3)
#undef FMA4
        }
        __syncthreads();
    }
#pragma unroll
    for (int i = 0; i < 4; ++i) {
        int gr = row0 + r0 + i;
        if (gr < S.M) {
#pragma unroll
            for (int j = 0; j < 4; ++j) {
                int gc = col0 + c0 + 32 * j;
                float v = acc[i][j];
                if (S.bias) v += S.bias[gc];
                if (S.relu) v = fmaxf(v, 0.f);
                S.C[(size_t)gr * S.N + gc] = v;
            }
        }
    }
}

// ---------------------------------------------------------------------------
// channel sums + attention scales + fused concat
// ---------------------------------------------------------------------------
struct SumArgs {
    const float* p[8];
    int cnt[8];
};

__global__ __launch_bounds__(256) void sum8_kernel(SumArgs args, float* __restrict__ sums) {
    __shared__ float red[256];
    const int ch = blockIdx.y;
    const float* x = args.p[ch];
    const int count = args.cnt[ch];
    float s = 0.f;
    for (int i = blockIdx.x * 256 + threadIdx.x; i < count; i += gridDim.x * 256) s += x[i];
    red[threadIdx.x] = s;
    __syncthreads();
    for (int off = 128; off > 0; off >>= 1) {
        if (threadIdx.x < off) red[threadIdx.x] += red[threadIdx.x + off];
        __syncthreads();
    }
    if (threadIdx.x == 0) atomicAdd(&sums[ch], red[0]);
}

__global__ void att_kernel(const float* __restrict__ sums,
                           const float* __restrict__ mW1, const float* __restrict__ mb1,
                           const float* __restrict__ mW2, const float* __restrict__ mb2,
                           const float* __restrict__ dW1, const float* __restrict__ db1,
                           const float* __restrict__ dW2, const float* __restrict__ db2,
                           float* __restrict__ scales) {
    if (threadIdx.x != 0 || blockIdx.x != 0) return;
    float mean[4], a[4];
    const float invM = 1.0f / (128.f * (float)NM_);
    for (int c = 0; c < 4; ++c) mean[c] = sums[c] * invM;
    for (int i = 0; i < 4; ++i) {
        float v = mb1[i];
        for (int j = 0; j < 4; ++j) v += mW1[i * 4 + j] * mean[j];
        a[i] = fmaxf(v, 0.f);
    }
    for (int c = 0; c < 4; ++c) {
        float v = mb2[c];
        for (int j = 0; j < 4; ++j) v += mW2[c * 4 + j] * a[j];
        scales[c] = 1.f / (1.f + expf(-v));
    }
    const float invD = 1.0f / (128.f * (float)ND_);
    float md[2] = {(sums[4] + sums[6]) * invD, (sums[5] + sums[7]) * invD};
    float ad[2];
    for (int i = 0; i < 2; ++i) {
        float v = db1[i];
        for (int j = 0; j < 2; ++j) v += dW1[i * 2 + j] * md[j];
        ad[i] = fmaxf(v, 0.f);
    }
    for (int c = 0; c < 2; ++c) {
        float v = db2[c];
        for (int j = 0; j < 2; ++j) v += dW2[c * 2 + j] * ad[j];
        scales[4 + c] = 1.f / (1.f + expf(-v));
    }
}

#define MCAT (NM_ * 512)
#define DCAT (ND_ * 256)

__global__ void cat_all(const float* __restrict__ l1, const float* __restrict__ l2,
                        const float* __restrict__ scales, float* __restrict__ catm,
                        float* __restrict__ catd) {
    int idx = blockIdx.x * 256 + threadIdx.x;
    if (idx < MCAT) {
        int i = idx >> 9;
        int k = idx & 511;
        int c = k >> 7;
        int j = k & 127;
        const float* p = (c == 0) ? l1 : (c == 1) ? l2
                         : (c == 2) ? l1 + (size_t)1043 * D128 : l2 + (size_t)1043 * D128;
        catm[idx] = fmaxf(scales[c] * p[(size_t)i * D128 + j], 0.f);
    } else if (idx < MCAT + DCAT) {
        int t = idx - MCAT;
        int i = t >> 8;
        int k = t & 255;
        int c = k >> 7;
        int j = k & 127;
        const float* pa = (c ? l2 : l1) + (size_t)2086 * D128;
        const float* pb = (c ? l2 : l1) + (size_t)4252 * D128;
        catd[t] = fmaxf(scales[4 + c] * (pa[(size_t)i * D128 + j] + pb[(size_t)i * D128 + j]), 0.f);
    }
}

// ---------------------------------------------------------------------------
extern "C" void kernel_launch(void* const* d_in, const int* in_sizes, int n_in,
                              void* d_out, int out_size, void* d_ws, size_t ws_size,
                              hipStream_t stream) {
    const float* mirna_x = (const float*)d_in[0];
    const float* drug_x  = (const float*)d_in[1];
    float* out = (float*)d_out;
    (void)in_sizes; (void)n_in; (void)out_size; (void)ws_size;

    char* ws = (char*)d_ws;
    auto AL = [](size_t x) { return (x + 255) & ~(size_t)255; };
    size_t o = 0;
    int2* spair = (int2*)(ws + o);   o += AL((size_t)ETOT * 8);
    int* cnt = (int*)(ws + o);       o += AL((size_t)NTOT * 4);
    int* rowptr = (int*)(ws + o);    o += AL((size_t)(NTOT + 4) * 4);
    float* dinv = (float*)(ws + o);  o += AL((size_t)NTOT * 4);
    float* sums = (float*)(ws + o);  o += 256;
    float* scales = (float*)(ws + o); o += 256;
    float* hbuf = (float*)(ws + o);  o += AL((size_t)NTOT * D128 * 4);
    float* l1out = (float*)(ws + o); o += AL((size_t)NTOT * D128 * 4);
    float* l2out = (float*)(ws + o); o += AL((size_t)NTOT * D128 * 4);
    // overlaid region R: {pcnt,pdeg,cum} then {catb,fush1}
    const size_t R = o;
    int*   pcnt = (int*)(ws + R);
    float* pdeg = (float*)(ws + R + AL((size_t)NBH * NTOT * 4));
    int*   cum  = (int*)(ws + R + 2 * AL((size_t)NBH * NTOT * 4));
    float* catb_m = (float*)(ws + R);
    float* catb_d = (float*)(ws + R + AL((size_t)NM_ * 512 * 4));
    float* fush1_m = (float*)(ws + R + AL((size_t)NM_ * 512 * 4) + AL((size_t)ND_ * 256 * 4));
    float* fush1_d = fush1_m + (size_t)NM_ * 256;

    ViewArgs va;
    const int vb_in[4] = {2, 8, 14, 20};
    int nn[4] = {NM_, NM_, ND_, ND_};
    int ee[4] = {EM_, EM_, ED_, ED_};
    int cn = 0, ce = 0;
    for (int v = 0; v < 4; ++v) {
        va.edge[v] = (const int*)d_in[vb_in[v]];
        va.w[v] = (const float*)d_in[vb_in[v] + 1];
        va.n[v] = nn[v];
        va.E[v] = ee[v];
        va.cumn[v] = cn;
        va.cumE[v] = ce;
        va.rpo[v] = cn + v;
        cn += nn[v];
        ce += ee[v];
    }
    va.cumn[4] = cn;
    va.cumE[4] = ce;

    hipMemsetAsync(sums, 0, 8 * 4, stream);

    // ---- CSR build (all views) ----
    hist_b<<<256, 1024, 0, stream>>>(va, pcnt, pdeg);
    colred_b<<<(NTOT + 255) / 256, 256, 0, stream>>>(va, pcnt, pdeg, cnt, dinv);
    scan_b<<<4, 256, 0, stream>>>(va, cnt, rowptr);
    cum_b<<<(NTOT + 255) / 256, 256, 0, stream>>>(va, pcnt, rowptr, cum);
    fill2_b<<<256, 1024, 0, stream>>>(va, dinv, cum, spair);

    // ---- layer GEMMs + fused aggregation ----
    auto feat_gemm = [&](int layer, const float* l1src) {
        GArgs ga;
        ga.nseg = 4;
        int blk = 0;
        for (int v = 0; v < 4; ++v) {
            GSeg& S = ga.s[v];
            S.A = (layer == 1) ? ((v < 2) ? mirna_x : drug_x)
                               : l1src + (size_t)va.cumn[v] * D128;
            S.W = (const float*)d_in[vb_in[v] + (layer == 1 ? 2 : 4)];
            S.bias = nullptr;
            S.C = hbuf + (size_t)va.cumn[v] * D128;
            S.M = va.n[v]; S.N = 128; S.K = 128;
            S.rowblks = (va.n[v] + 31) / 32;
            S.blk0 = blk; S.relu = 0;
            blk += S.rowblks;
        }
        gemm_b<<<blk, 256, 0, stream>>>(ga);
    };
    BiasArr b1, b2;
    for (int v = 0; v < 4; ++v) {
        b1.b[v] = (const float*)d_in[vb_in[v] + 3];
        b2.b[v] = (const float*)d_in[vb_in[v] + 5];
    }

    feat_gemm(1, nullptr);
    agg_b<<<NTOT, 128, 0, stream>>>(va, spair, rowptr, hbuf, b1, l1out);
    feat_gemm(2, l1out);
    agg_b<<<NTOT, 128, 0, stream>>>(va, spair, rowptr, hbuf, b2, l2out);

    // ---- channel sums -> attention scales ----
    SumArgs sa;
    sa.p[0] = l1out;                      sa.p[1] = l2out;
    sa.p[2] = l1out + (size_t)1043 * 128; sa.p[3] = l2out + (size_t)1043 * 128;
    sa.p[4] = l1out + (size_t)2086 * 128; sa.p[5] = l2out + (size_t)2086 * 128;
    sa.p[6] = l1out + (size_t)4252 * 128; sa.p[7] = l2out + (size_t)4252 * 128;
    sa.cnt[0] = sa.cnt[1] = sa.cnt[2] = sa.cnt[3] = NM_ * D128;
    sa.cnt[4] = sa.cnt[5] = sa.cnt[6] = sa.cnt[7] = ND_ * D128;
    sum8_kernel<<<dim3(16, 8), 256, 0, stream>>>(sa, sums);
    att_kernel<<<1, 64, 0, stream>>>(sums,
        (const float*)d_in[26], (const float*)d_in[27], (const float*)d_in[28], (const float*)d_in[29],
        (const float*)d_in[30], (const float*)d_in[31], (const float*)d_in[32], (const float*)d_in[33],
        scales);

    // ---- concat (scaled, fused m+d) ----
    cat_all<<<(MCAT + DCAT + 255) / 256, 256, 0, stream>>>(l1out, l2out, scales, catb_m, catb_d);

    // ---- fusion GEMMs (m + d batched) ----
    {
        GArgs ga;
        ga.nseg = 2;
        ga.s[0] = {catb_m, (const float*)d_in[34], (const float*)d_in[35], fush1_m,
                   NM_, 256, 512, 33, 0, 1};
        ga.s[1] = {catb_d, (const float*)d_in[38], (const float*)d_in[39], fush1_d,
                   ND_, 256, 256, 68, 66, 1};
        gemm_b<<<66 + 136, 256, 0, stream>>>(ga);
    }
    {
        GArgs ga;
        ga.nseg = 2;
        ga.s[0] = {fush1_m, (const float*)d_in[36], (const float*)d_in[37], out,
                   NM_, 128, 256, 33, 0, 1};
        ga.s[1] = {fush1_d, (const float*)d_in[40], (const float*)d_in[41],
                   out + (size_t)NM_ * D128, ND_, 128, 256, 68, 33, 1};
        gemm_b<<<33 + 68, 256, 0, stream>>>(ga);
    }
}

// Round 13
// 250.291 us; speedup vs baseline: 2.7070x; 1.0866x over previous
//
#include <hip/hip_runtime.h>
#include <math.h>

#define D128 128
#define NM_ 1043
#define ND_ 2166
#define EM_ 300000
#define ED_ 600000
#define NBH 64              // chunks per view (hist + fill)
#define NMAX 2176
#define NTOT 6418           // 2*1043 + 2*2166
#define ETOT 1800000

struct ViewArgs {
    const int* edge[4];
    const float* w[4];
    int n[4], E[4];
    int cumn[5];
    int cumE[5];
    int rpo[4];
};

struct BiasArr { const float* b[4]; };

// ---------------------------------------------------------------------------
// CSR build, pass 1: per-chunk privatized histograms (LDS atomics only)
// ---------------------------------------------------------------------------
__global__ __launch_bounds__(1024) void hist_b(ViewArgs va, int* __restrict__ pcnt,
                                               float* __restrict__ pdeg) {
    __shared__ int lc[NMAX];
    __shared__ float ld[NMAX];
    const int view = blockIdx.x >> 6, vb = blockIdx.x & 63;
    const int n = va.n[view], E = va.E[view];
    const int* edge = va.edge[view];
    const float* w = va.w[view];
    for (int i = threadIdx.x; i < n; i += 1024) { lc[i] = 0; ld[i] = 0.f; }
    __syncthreads();
    const int per = (E + NBH - 1) / NBH;
    const int b = vb * per, e = min(E, b + per);
    for (int i = b + threadIdx.x; i < e; i += 1024) {
        int dst = edge[E + i];
        atomicAdd(&lc[dst], 1);
        atomicAdd(&ld[dst], w[i]);
    }
    __syncthreads();
    int* pc = pcnt + (size_t)NBH * va.cumn[view] + (size_t)vb * n;
    float* pd = pdeg + (size_t)NBH * va.cumn[view] + (size_t)vb * n;
    for (int i = threadIdx.x; i < n; i += 1024) { pc[i] = lc[i]; pd[i] = ld[i]; }
}

__global__ void colred_b(ViewArgs va, const int* __restrict__ pcnt,
                         const float* __restrict__ pdeg, int* __restrict__ cnt,
                         float* __restrict__ dinv) {
    int i = blockIdx.x * 256 + threadIdx.x;
    if (i >= NTOT) return;
    int view = 0;
    while (view < 3 && i >= va.cumn[view + 1]) ++view;
    const int il = i - va.cumn[view], n = va.n[view];
    const int* pc = pcnt + (size_t)NBH * va.cumn[view];
    const float* pd = pdeg + (size_t)NBH * va.cumn[view];
    int c = 0;
    float dg = 0.f;
    for (int b = 0; b < NBH; ++b) {
        c += pc[(size_t)b * n + il];
        dg += pd[(size_t)b * n + il];
    }
    cnt[i] = c;
    dinv[i] = dg > 0.f ? 1.0f / sqrtf(dg) : 0.f;
}

// lean per-view exclusive scan: serial local sums + shfl wave scan
__global__ void scan_b(ViewArgs va, const int* __restrict__ cnt, int* __restrict__ rowptr) {
    __shared__ int wsum[4];
    const int view = blockIdx.x;
    const int n = va.n[view];
    const int* c = cnt + va.cumn[view];
    int* rp = rowptr + va.rpo[view];
    const int tid = threadIdx.x;
    const int per = (n + 255) / 256;
    const int b0 = tid * per, e0 = min(n, b0 + per);
    int s = 0;
    for (int i = b0; i < e0; ++i) s += c[i];
    const int lane = tid & 63, wid = tid >> 6;
    int sc = s;
    for (int off = 1; off < 64; off <<= 1) {
        int t = __shfl_up(sc, off);
        if (lane >= off) sc += t;
    }
    if (lane == 63) wsum[wid] = sc;
    __syncthreads();
    int wbase = 0;
    for (int wv = 0; wv < wid; ++wv) wbase += wsum[wv];
    int run = wbase + sc - s;       // exclusive base for this thread's range
    if (tid == 0) rp[0] = 0;
    for (int i = b0; i < e0; ++i) {
        run += c[i];
        rp[i + 1] = run;
    }
}

// per-(chunk,bin) bases: cum[c][i] = rowptr[i] + sum_{c'<c} pcnt[c'][i]
__global__ void cum_b(ViewArgs va, const int* __restrict__ pcnt,
                      const int* __restrict__ rowptr, int* __restrict__ cum) {
    int i = blockIdx.x * 256 + threadIdx.x;
    if (i >= NTOT) return;
    int view = 0;
    while (view < 3 && i >= va.cumn[view + 1]) ++view;
    const int il = i - va.cumn[view], n = va.n[view];
    const int* pc = pcnt + (size_t)NBH * va.cumn[view];
    int* cm = cum + (size_t)NBH * va.cumn[view];
    int run = rowptr[va.rpo[view] + il];
    for (int b = 0; b < NBH; ++b) {
        cm[(size_t)b * n + il] = run;
        run += pc[(size_t)b * n + il];
    }
}

// CSR build pass 2: place (src, norm) pairs; int2 writes
__global__ __launch_bounds__(1024) void fill2_b(ViewArgs va, const float* __restrict__ dinv,
                                                const int* __restrict__ cum,
                                                int2* __restrict__ spair) {
    __shared__ int lc[NMAX];
    const int view = blockIdx.x >> 6, vb = blockIdx.x & 63;
    const int n = va.n[view], E = va.E[view];
    const int* edge = va.edge[view];
    const float* w = va.w[view];
    const int* cm = cum + (size_t)NBH * va.cumn[view] + (size_t)vb * n;
    const float* dv = dinv + va.cumn[view];
    int2* sp = spair + va.cumE[view];
    for (int i = threadIdx.x; i < n; i += 1024) lc[i] = cm[i];
    __syncthreads();
    const int per = (E + NBH - 1) / NBH;
    const int b = vb * per, e = min(E, b + per);
    for (int i = b + threadIdx.x; i < e; i += 1024) {
        int src = edge[i];
        int dst = edge[E + i];
        int pos = atomicAdd(&lc[dst], 1);
        float nrm = dv[src] * w[i] * dv[dst];
        sp[pos] = make_int2(src, __float_as_int(nrm));
    }
}

// ---------------------------------------------------------------------------
// fused edge aggregation + bias + relu: one block (128 thr) per node with
// bijective XCD swizzle. Unroll-8 inner loop: 4x int4 metadata loads + 8
// independent gathers in flight per wave (deeper MLP for the MSHR-bound
// L2-gather regime).
// ---------------------------------------------------------------------------
__global__ __launch_bounds__(128) void agg_b(ViewArgs va, const int2* __restrict__ spair,
                                             const int* __restrict__ rowptr,
                                             const float* __restrict__ h, BiasArr ba,
                                             float* __restrict__ outbuf) {
    // bijective XCD swizzle: NTOT = 8*802 + 2
    const int xcd = blockIdx.x & 7, k = blockIdx.x >> 3;
    const int nf = (xcd < 2 ? xcd * 803 : 2 * 803 + (xcd - 2) * 802) + k;
    int view = 0;
    while (view < 3 && nf >= va.cumn[view + 1]) ++view;
    const int ln = nf - va.cumn[view];
    const int* rp = rowptr + va.rpo[view];
    const int beg = rp[ln], end = rp[ln + 1];
    const int2* sp = spair + va.cumE[view];
    const float* hb = h + (size_t)va.cumn[view] * D128;
    const int tid = threadIdx.x;
    float a0 = 0.f, a1 = 0.f, a2 = 0.f, a3 = 0.f;
    int i = beg;
    for (; i + 8 <= end; i += 8) {
        int4 q0 = *(const int4*)(sp + i);
        int4 q1 = *(const int4*)(sp + i + 2);
        int4 q2 = *(const int4*)(sp + i + 4);
        int4 q3 = *(const int4*)(sp + i + 6);
        float h0 = hb[(size_t)q0.x * D128 + tid];
        float h1 = hb[(size_t)q0.z * D128 + tid];
        float h2 = hb[(size_t)q1.x * D128 + tid];
        float h3 = hb[(size_t)q1.z * D128 + tid];
        float h4 = hb[(size_t)q2.x * D128 + tid];
        float h5 = hb[(size_t)q2.z * D128 + tid];
        float h6 = hb[(size_t)q3.x * D128 + tid];
        float h7 = hb[(size_t)q3.z * D128 + tid];
        a0 = fmaf(__int_as_float(q0.y), h0, a0);
        a1 = fmaf(__int_as_float(q0.w), h1, a1);
        a2 = fmaf(__int_as_float(q1.y), h2, a2);
        a3 = fmaf(__int_as_float(q1.w), h3, a3);
        a0 = fmaf(__int_as_float(q2.y), h4, a0);
        a1 = fmaf(__int_as_float(q2.w), h5, a1);
        a2 = fmaf(__int_as_float(q3.y), h6, a2);
        a3 = fmaf(__int_as_float(q3.w), h7, a3);
    }
    for (; i + 4 <= end; i += 4) {
        int2 p0 = sp[i], p1 = sp[i + 1], p2 = sp[i + 2], p3 = sp[i + 3];
        a0 = fmaf(__int_as_float(p0.y), hb[(size_t)p0.x * D128 + tid], a0);
        a1 = fmaf(__int_as_float(p1.y), hb[(size_t)p1.x * D128 + tid], a1);
        a2 = fmaf(__int_as_float(p2.y), hb[(size_t)p2.x * D128 + tid], a2);
        a3 = fmaf(__int_as_float(p3.y), hb[(size_t)p3.x * D128 + tid], a3);
    }
    for (; i < end; ++i)
        a0 = fmaf(__int_as_float(sp[i].y), hb[(size_t)sp[i].x * D128 + tid], a0);
    float v = (a0 + a1) + (a2 + a3);
    outbuf[(size_t)nf * D128 + tid] = fmaxf(v + ba.b[view][tid], 0.f);
}

// ---------------------------------------------------------------------------
// unified multi-segment GEMM: C[M,N] = A[M,K] @ W[N,K]^T (+bias, relu)
// ---------------------------------------------------------------------------
struct GSeg {
    const float* A;
    const float* W;
    const float* bias;
    float* C;
    int M, N, K, rowblks, blk0, relu;
};
struct GArgs { GSeg s[4]; int nseg; };

__global__ __launch_bounds__(256) void gemm_b(GArgs ga) {
    __shared__ float xs[32 * 64];
    __shared__ float wsm[128 * 64];
    int si = 0;
    while (si + 1 < ga.nseg && (int)blockIdx.x >= ga.s[si + 1].blk0) ++si;
    const GSeg S = ga.s[si];
    const int lb = blockIdx.x - S.blk0;
    const int rb = lb % S.rowblks, cb = lb / S.rowblks;
    const int row0 = rb * 32, col0 = cb * 128;
    const int tid = threadIdx.x;
    const int r0 = (tid >> 5) << 2;
    const int c0 = tid & 31;
    const int csw = (c0 & 7) << 2;
    float acc[4][4] = {};
    for (int kc = 0; kc < S.K; kc += 64) {
#pragma unroll
        for (int it = 0; it < 2; ++it) {
            int idx = tid + it * 256;
            int r = idx >> 4, k4 = (idx & 15) << 2;
            int gr = row0 + r;
            if (gr > S.M - 1) gr = S.M - 1;
            *(float4*)(xs + r * 64 + k4) =
                *(const float4*)(S.A + (size_t)gr * S.K + kc + k4);
        }
#pragma unroll
        for (int it = 0; it < 8; ++it) {
            int idx = tid + it * 256;
            int c = idx >> 4, k4 = (idx & 15) << 2;
            *(float4*)(wsm + c * 64 + (k4 ^ ((c & 7) << 2))) =
                *(const float4*)(S.W + (size_t)(col0 + c) * S.K + kc + k4);
        }
        __syncthreads();
#pragma unroll
        for (int k4 = 0; k4 < 64; k4 += 4) {
            float4 a0 = *(const float4*)(xs + (r0 + 0) * 64 + k4);
            float4 a1 = *(const float4*)(xs + (r0 + 1) * 64 + k4);
            float4 a2 = *(const float4*)(xs + (r0 + 2) * 64 + k4);
            float4 a3 = *(const float4*)(xs + (r0 + 3) * 64 + k4);
            const int sk = k4 ^ csw;
            float4 w0 = *(const float4*)(wsm + (c0 + 0) * 64 + sk);
            float4 w1 = *(const float4*)(wsm + (c0 + 32) * 64 + sk);
            float4 w2 = *(const float4*)(wsm + (c0 + 64) * 64 + sk);
            float4 w3 = *(const float4*)(wsm + (c0 + 96) * 64 + sk);
#define FMA4(i, av)                                                   \
            acc[i][0] = fmaf(av.x, w0.x, acc[i][0]); acc[i][0] = fmaf(av.y, w0.y, acc[i][0]); \
            acc[i][0] = fmaf(av.z, w0.z, acc[i][0]); acc[i][0] = fmaf(av.w, w0.w, acc[i][0]); \
            acc[i][1] = fmaf(av.x, w1.x, acc[i][1]); acc[i][1] = fmaf(av.y, w1.y, acc[i][1]); \
            acc[i][1] = fmaf(av.z, w1.z, acc[i][1]); acc[i][1] = fmaf(av.w, w1.w, acc[i][1]); \
            acc[i][2] = fmaf(av.x, w2.x, acc[i][2]); acc[i][2] = fmaf(av.y, w2.y, acc[i][2]); \
            acc[i][2] = fmaf(av.z, w2.z, acc[i][2]); acc[i][2] = fmaf(av.w, w2.w, acc[i][2]); \
            acc[i][3] = fmaf(av.x, w3.x, acc[i][3]); acc[i][3] = fmaf(av.y, w3.y, acc[i][3]); \
            acc[i][3] = fmaf(av.z, w3.z, acc[i][3]); acc[i][3] = fmaf(av.w, w3.w, acc[i][3]);
            FMA4(0, a0) FMA4(1, a1) FMA4(2, a2) FMA4(3, a3)
#undef FMA4
        }
        __syncthreads();
    }
#pragma unroll
    for (int i = 0; i < 4; ++i) {
        int gr = row0 + r0 + i;
        if (gr < S.M) {
#pragma unroll
            for (int j = 0; j < 4; ++j) {
                int gc = col0 + c0 + 32 * j;
                float v = acc[i][j];
                if (S.bias) v += S.bias[gc];
                if (S.relu) v = fmaxf(v, 0.f);
                S.C[(size_t)gr * S.N + gc] = v;
            }
        }
    }
}

// ---------------------------------------------------------------------------
// channel sums + attention scales + fused concat
// ---------------------------------------------------------------------------
struct SumArgs {
    const float* p[8];
    int cnt[8];
};

__global__ __launch_bounds__(256) void sum8_kernel(SumArgs args, float* __restrict__ sums) {
    __shared__ float red[256];
    const int ch = blockIdx.y;
    const float* x = args.p[ch];
    const int count = args.cnt[ch];
    float s = 0.f;
    for (int i = blockIdx.x * 256 + threadIdx.x; i < count; i += gridDim.x * 256) s += x[i];
    red[threadIdx.x] = s;
    __syncthreads();
    for (int off = 128; off > 0; off >>= 1) {
        if (threadIdx.x < off) red[threadIdx.x] += red[threadIdx.x + off];
        __syncthreads();
    }
    if (threadIdx.x == 0) atomicAdd(&sums[ch], red[0]);
}

__global__ void att_kernel(const float* __restrict__ sums,
                           const float* __restrict__ mW1, const float* __restrict__ mb1,
                           const float* __restrict__ mW2, const float* __restrict__ mb2,
                           const float* __restrict__ dW1, const float* __restrict__ db1,
                           const float* __restrict__ dW2, const float* __restrict__ db2,
                           float* __restrict__ scales) {
    if (threadIdx.x != 0 || blockIdx.x != 0) return;
    float mean[4], a[4];
    const float invM = 1.0f / (128.f * (float)NM_);
    for (int c = 0; c < 4; ++c) mean[c] = sums[c] * invM;
    for (int i = 0; i < 4; ++i) {
        float v = mb1[i];
        for (int j = 0; j < 4; ++j) v += mW1[i * 4 + j] * mean[j];
        a[i] = fmaxf(v, 0.f);
    }
    for (int c = 0; c < 4; ++c) {
        float v = mb2[c];
        for (int j = 0; j < 4; ++j) v += mW2[c * 4 + j] * a[j];
        scales[c] = 1.f / (1.f + expf(-v));
    }
    const float invD = 1.0f / (128.f * (float)ND_);
    float md[2] = {(sums[4] + sums[6]) * invD, (sums[5] + sums[7]) * invD};
    float ad[2];
    for (int i = 0; i < 2; ++i) {
        float v = db1[i];
        for (int j = 0; j < 2; ++j) v += dW1[i * 2 + j] * md[j];
        ad[i] = fmaxf(v, 0.f);
    }
    for (int c = 0; c < 2; ++c) {
        float v = db2[c];
        for (int j = 0; j < 2; ++j) v += dW2[c * 2 + j] * ad[j];
        scales[4 + c] = 1.f / (1.f + expf(-v));
    }
}

#define MCAT (NM_ * 512)
#define DCAT (ND_ * 256)

__global__ void cat_all(const float* __restrict__ l1, const float* __restrict__ l2,
                        const float* __restrict__ scales, float* __restrict__ catm,
                        float* __restrict__ catd) {
    int idx = blockIdx.x * 256 + threadIdx.x;
    if (idx < MCAT) {
        int i = idx >> 9;
        int k = idx & 511;
        int c = k >> 7;
        int j = k & 127;
        const float* p = (c == 0) ? l1 : (c == 1) ? l2
                         : (c == 2) ? l1 + (size_t)1043 * D128 : l2 + (size_t)1043 * D128;
        catm[idx] = fmaxf(scales[c] * p[(size_t)i * D128 + j], 0.f);
    } else if (idx < MCAT + DCAT) {
        int t = idx - MCAT;
        int i = t >> 8;
        int k = t & 255;
        int c = k >> 7;
        int j = k & 127;
        const float* pa = (c ? l2 : l1) + (size_t)2086 * D128;
        const float* pb = (c ? l2 : l1) + (size_t)4252 * D128;
        catd[t] = fmaxf(scales[4 + c] * (pa[(size_t)i * D128 + j] + pb[(size_t)i * D128 + j]), 0.f);
    }
}

// ---------------------------------------------------------------------------
extern "C" void kernel_launch(void* const* d_in, const int* in_sizes, int n_in,
                              void* d_out, int out_size, void* d_ws, size_t ws_size,
                              hipStream_t stream) {
    const float* mirna_x = (const float*)d_in[0];
    const float* drug_x  = (const float*)d_in[1];
    float* out = (float*)d_out;
    (void)in_sizes; (void)n_in; (void)out_size; (void)ws_size;

    char* ws = (char*)d_ws;
    auto AL = [](size_t x) { return (x + 255) & ~(size_t)255; };
    size_t o = 0;
    int2* spair = (int2*)(ws + o);   o += AL((size_t)ETOT * 8);
    int* cnt = (int*)(ws + o);       o += AL((size_t)NTOT * 4);
    int* rowptr = (int*)(ws + o);    o += AL((size_t)(NTOT + 4) * 4);
    float* dinv = (float*)(ws + o);  o += AL((size_t)NTOT * 4);
    float* sums = (float*)(ws + o);  o += 256;
    float* scales = (float*)(ws + o); o += 256;
    float* hbuf = (float*)(ws + o);  o += AL((size_t)NTOT * D128 * 4);
    float* l1out = (float*)(ws + o); o += AL((size_t)NTOT * D128 * 4);
    float* l2out = (float*)(ws + o); o += AL((size_t)NTOT * D128 * 4);
    // overlaid region R: {pcnt,pdeg,cum} then {catb,fush1}
    const size_t R = o;
    int*   pcnt = (int*)(ws + R);
    float* pdeg = (float*)(ws + R + AL((size_t)NBH * NTOT * 4));
    int*   cum  = (int*)(ws + R + 2 * AL((size_t)NBH * NTOT * 4));
    float* catb_m = (float*)(ws + R);
    float* catb_d = (float*)(ws + R + AL((size_t)NM_ * 512 * 4));
    float* fush1_m = (float*)(ws + R + AL((size_t)NM_ * 512 * 4) + AL((size_t)ND_ * 256 * 4));
    float* fush1_d = fush1_m + (size_t)NM_ * 256;

    ViewArgs va;
    const int vb_in[4] = {2, 8, 14, 20};
    int nn[4] = {NM_, NM_, ND_, ND_};
    int ee[4] = {EM_, EM_, ED_, ED_};
    int cn = 0, ce = 0;
    for (int v = 0; v < 4; ++v) {
        va.edge[v] = (const int*)d_in[vb_in[v]];
        va.w[v] = (const float*)d_in[vb_in[v] + 1];
        va.n[v] = nn[v];
        va.E[v] = ee[v];
        va.cumn[v] = cn;
        va.cumE[v] = ce;
        va.rpo[v] = cn + v;
        cn += nn[v];
        ce += ee[v];
    }
    va.cumn[4] = cn;
    va.cumE[4] = ce;

    hipMemsetAsync(sums, 0, 8 * 4, stream);

    // ---- CSR build (all views) ----
    hist_b<<<256, 1024, 0, stream>>>(va, pcnt, pdeg);
    colred_b<<<(NTOT + 255) / 256, 256, 0, stream>>>(va, pcnt, pdeg, cnt, dinv);
    scan_b<<<4, 256, 0, stream>>>(va, cnt, rowptr);
    cum_b<<<(NTOT + 255) / 256, 256, 0, stream>>>(va, pcnt, rowptr, cum);
    fill2_b<<<256, 1024, 0, stream>>>(va, dinv, cum, spair);

    // ---- layer GEMMs + fused aggregation ----
    auto feat_gemm = [&](int layer, const float* l1src) {
        GArgs ga;
        ga.nseg = 4;
        int blk = 0;
        for (int v = 0; v < 4; ++v) {
            GSeg& S = ga.s[v];
            S.A = (layer == 1) ? ((v < 2) ? mirna_x : drug_x)
                               : l1src + (size_t)va.cumn[v] * D128;
            S.W = (const float*)d_in[vb_in[v] + (layer == 1 ? 2 : 4)];
            S.bias = nullptr;
            S.C = hbuf + (size_t)va.cumn[v] * D128;
            S.M = va.n[v]; S.N = 128; S.K = 128;
            S.rowblks = (va.n[v] + 31) / 32;
            S.blk0 = blk; S.relu = 0;
            blk += S.rowblks;
        }
        gemm_b<<<blk, 256, 0, stream>>>(ga);
    };
    BiasArr b1, b2;
    for (int v = 0; v < 4; ++v) {
        b1.b[v] = (const float*)d_in[vb_in[v] + 3];
        b2.b[v] = (const float*)d_in[vb_in[v] + 5];
    }

    feat_gemm(1, nullptr);
    agg_b<<<NTOT, 128, 0, stream>>>(va, spair, rowptr, hbuf, b1, l1out);
    feat_gemm(2, l1out);
    agg_b<<<NTOT, 128, 0, stream>>>(va, spair, rowptr, hbuf, b2, l2out);

    // ---- channel sums -> attention scales ----
    SumArgs sa;
    sa.p[0] = l1out;                      sa.p[1] = l2out;
    sa.p[2] = l1out + (size_t)1043 * 128; sa.p[3] = l2out + (size_t)1043 * 128;
    sa.p[4] = l1out + (size_t)2086 * 128; sa.p[5] = l2out + (size_t)2086 * 128;
    sa.p[6] = l1out + (size_t)4252 * 128; sa.p[7] = l2out + (size_t)4252 * 128;
    sa.cnt[0] = sa.cnt[1] = sa.cnt[2] = sa.cnt[3] = NM_ * D128;
    sa.cnt[4] = sa.cnt[5] = sa.cnt[6] = sa.cnt[7] = ND_ * D128;
    sum8_kernel<<<dim3(16, 8), 256, 0, stream>>>(sa, sums);
    att_kernel<<<1, 64, 0, stream>>>(sums,
        (const float*)d_in[26], (const float*)d_in[27], (const float*)d_in[28], (const float*)d_in[29],
        (const float*)d_in[30], (const float*)d_in[31], (const float*)d_in[32], (const float*)d_in[33],
        scales);

    // ---- concat (scaled, fused m+d) ----
    cat_all<<<(MCAT + DCAT + 255) / 256, 256, 0, stream>>>(l1out, l2out, scales, catb_m, catb_d);

    // ---- fusion GEMMs (m + d batched) ----
    {
        GArgs ga;
        ga.nseg = 2;
        ga.s[0] = {catb_m, (const float*)d_in[34], (const float*)d_in[35], fush1_m,
                   NM_, 256, 512, 33, 0, 1};
        ga.s[1] = {catb_d, (const float*)d_in[38], (const float*)d_in[39], fush1_d,
                   ND_, 256, 256, 68, 66, 1};
        gemm_b<<<66 + 136, 256, 0, stream>>>(ga);
    }
    {
        GArgs ga;
        ga.nseg = 2;
        ga.s[0] = {fush1_m, (const float*)d_in[36], (const float*)d_in[37], out,
                   NM_, 128, 256, 33, 0, 1};
        ga.s[1] = {fush1_d, (const float*)d_in[40], (const float*)d_in[41],
                   out + (size_t)NM_ * D128, ND_, 128, 256, 68, 33, 1};
        gemm_b<<<33 + 68, 256, 0, stream>>>(ga);
    }
}

// Round 14
// 237.490 us; speedup vs baseline: 2.8529x; 1.0539x over previous
//
#include <hip/hip_runtime.h>
#include <math.h>

#define D128 128
#define NM_ 1043
#define ND_ 2166
#define EM_ 300000
#define ED_ 600000
#define NBH 64              // chunks per view (hist + fill)
#define NMAX 2176
#define NTOT 6418           // 2*1043 + 2*2166
#define ETOT 1800000

struct ViewArgs {
    const int* edge[4];
    const float* w[4];
    int n[4], E[4];
    int cumn[5];
    int cumE[5];
    int rpo[4];
};

struct BiasArr { const float* b[4]; };

// ---------------------------------------------------------------------------
// CSR build, pass 1: per-chunk privatized histograms (LDS atomics only)
// ---------------------------------------------------------------------------
__global__ __launch_bounds__(1024) void hist_b(ViewArgs va, int* __restrict__ pcnt,
                                               float* __restrict__ pdeg) {
    __shared__ int lc[NMAX];
    __shared__ float ld[NMAX];
    const int view = blockIdx.x >> 6, vb = blockIdx.x & 63;
    const int n = va.n[view], E = va.E[view];
    const int* edge = va.edge[view];
    const float* w = va.w[view];
    for (int i = threadIdx.x; i < n; i += 1024) { lc[i] = 0; ld[i] = 0.f; }
    __syncthreads();
    const int per = (E + NBH - 1) / NBH;
    const int b = vb * per, e = min(E, b + per);
    for (int i = b + threadIdx.x; i < e; i += 1024) {
        int dst = edge[E + i];
        atomicAdd(&lc[dst], 1);
        atomicAdd(&ld[dst], w[i]);
    }
    __syncthreads();
    int* pc = pcnt + (size_t)NBH * va.cumn[view] + (size_t)vb * n;
    float* pd = pdeg + (size_t)NBH * va.cumn[view] + (size_t)vb * n;
    for (int i = threadIdx.x; i < n; i += 1024) { pc[i] = lc[i]; pd[i] = ld[i]; }
}

__global__ void colred_b(ViewArgs va, const int* __restrict__ pcnt,
                         const float* __restrict__ pdeg, int* __restrict__ cnt,
                         float* __restrict__ dinv) {
    int i = blockIdx.x * 256 + threadIdx.x;
    if (i >= NTOT) return;
    int view = 0;
    while (view < 3 && i >= va.cumn[view + 1]) ++view;
    const int il = i - va.cumn[view], n = va.n[view];
    const int* pc = pcnt + (size_t)NBH * va.cumn[view];
    const float* pd = pdeg + (size_t)NBH * va.cumn[view];
    int c = 0;
    float dg = 0.f;
    for (int b = 0; b < NBH; ++b) {
        c += pc[(size_t)b * n + il];
        dg += pd[(size_t)b * n + il];
    }
    cnt[i] = c;
    dinv[i] = dg > 0.f ? 1.0f / sqrtf(dg) : 0.f;
}

// lean per-view exclusive scan: serial local sums + shfl wave scan
__global__ void scan_b(ViewArgs va, const int* __restrict__ cnt, int* __restrict__ rowptr) {
    __shared__ int wsum[4];
    const int view = blockIdx.x;
    const int n = va.n[view];
    const int* c = cnt + va.cumn[view];
    int* rp = rowptr + va.rpo[view];
    const int tid = threadIdx.x;
    const int per = (n + 255) / 256;
    const int b0 = tid * per, e0 = min(n, b0 + per);
    int s = 0;
    for (int i = b0; i < e0; ++i) s += c[i];
    const int lane = tid & 63, wid = tid >> 6;
    int sc = s;
    for (int off = 1; off < 64; off <<= 1) {
        int t = __shfl_up(sc, off);
        if (lane >= off) sc += t;
    }
    if (lane == 63) wsum[wid] = sc;
    __syncthreads();
    int wbase = 0;
    for (int wv = 0; wv < wid; ++wv) wbase += wsum[wv];
    int run = wbase + sc - s;       // exclusive base for this thread's range
    if (tid == 0) rp[0] = 0;
    for (int i = b0; i < e0; ++i) {
        run += c[i];
        rp[i + 1] = run;
    }
}

// per-(chunk,bin) bases: cum[c][i] = rowptr[i] + sum_{c'<c} pcnt[c'][i]
__global__ void cum_b(ViewArgs va, const int* __restrict__ pcnt,
                      const int* __restrict__ rowptr, int* __restrict__ cum) {
    int i = blockIdx.x * 256 + threadIdx.x;
    if (i >= NTOT) return;
    int view = 0;
    while (view < 3 && i >= va.cumn[view + 1]) ++view;
    const int il = i - va.cumn[view], n = va.n[view];
    const int* pc = pcnt + (size_t)NBH * va.cumn[view];
    int* cm = cum + (size_t)NBH * va.cumn[view];
    int run = rowptr[va.rpo[view] + il];
    for (int b = 0; b < NBH; ++b) {
        cm[(size_t)b * n + il] = run;
        run += pc[(size_t)b * n + il];
    }
}

// CSR build pass 2: place (src, norm) pairs; int2 writes
__global__ __launch_bounds__(1024) void fill2_b(ViewArgs va, const float* __restrict__ dinv,
                                                const int* __restrict__ cum,
                                                int2* __restrict__ spair) {
    __shared__ int lc[NMAX];
    const int view = blockIdx.x >> 6, vb = blockIdx.x & 63;
    const int n = va.n[view], E = va.E[view];
    const int* edge = va.edge[view];
    const float* w = va.w[view];
    const int* cm = cum + (size_t)NBH * va.cumn[view] + (size_t)vb * n;
    const float* dv = dinv + va.cumn[view];
    int2* sp = spair + va.cumE[view];
    for (int i = threadIdx.x; i < n; i += 1024) lc[i] = cm[i];
    __syncthreads();
    const int per = (E + NBH - 1) / NBH;
    const int b = vb * per, e = min(E, b + per);
    for (int i = b + threadIdx.x; i < e; i += 1024) {
        int src = edge[i];
        int dst = edge[E + i];
        int pos = atomicAdd(&lc[dst], 1);
        float nrm = dv[src] * w[i] * dv[dst];
        sp[pos] = make_int2(src, __float_as_int(nrm));
    }
}

// ---------------------------------------------------------------------------
// fused edge aggregation + bias + relu: one block (128 thr) per node with
// bijective XCD swizzle. Unroll-16 inner loop: 8x int4 metadata loads + 16
// independent gathers in flight per wave (ILP for the MSHR-bound regime;
// r13 measured 4->8 in-flight = 61->50us).
// ---------------------------------------------------------------------------
__global__ __launch_bounds__(128) void agg_b(ViewArgs va, const int2* __restrict__ spair,
                                             const int* __restrict__ rowptr,
                                             const float* __restrict__ h, BiasArr ba,
                                             float* __restrict__ outbuf) {
    // bijective XCD swizzle: NTOT = 8*802 + 2
    const int xcd = blockIdx.x & 7, k = blockIdx.x >> 3;
    const int nf = (xcd < 2 ? xcd * 803 : 2 * 803 + (xcd - 2) * 802) + k;
    int view = 0;
    while (view < 3 && nf >= va.cumn[view + 1]) ++view;
    const int ln = nf - va.cumn[view];
    const int* rp = rowptr + va.rpo[view];
    const int beg = rp[ln], end = rp[ln + 1];
    const int2* sp = spair + va.cumE[view];
    const float* hb = h + (size_t)va.cumn[view] * D128;
    const int tid = threadIdx.x;
    float a0 = 0.f, a1 = 0.f, a2 = 0.f, a3 = 0.f;
    int i = beg;
    for (; i + 16 <= end; i += 16) {
        int4 q0 = *(const int4*)(sp + i);
        int4 q1 = *(const int4*)(sp + i + 2);
        int4 q2 = *(const int4*)(sp + i + 4);
        int4 q3 = *(const int4*)(sp + i + 6);
        int4 q4 = *(const int4*)(sp + i + 8);
        int4 q5 = *(const int4*)(sp + i + 10);
        int4 q6 = *(const int4*)(sp + i + 12);
        int4 q7 = *(const int4*)(sp + i + 14);
        float h0 = hb[(size_t)q0.x * D128 + tid];
        float h1 = hb[(size_t)q0.z * D128 + tid];
        float h2 = hb[(size_t)q1.x * D128 + tid];
        float h3 = hb[(size_t)q1.z * D128 + tid];
        float h4 = hb[(size_t)q2.x * D128 + tid];
        float h5 = hb[(size_t)q2.z * D128 + tid];
        float h6 = hb[(size_t)q3.x * D128 + tid];
        float h7 = hb[(size_t)q3.z * D128 + tid];
        float h8 = hb[(size_t)q4.x * D128 + tid];
        float h9 = hb[(size_t)q4.z * D128 + tid];
        float hA = hb[(size_t)q5.x * D128 + tid];
        float hB = hb[(size_t)q5.z * D128 + tid];
        float hC = hb[(size_t)q6.x * D128 + tid];
        float hD = hb[(size_t)q6.z * D128 + tid];
        float hE = hb[(size_t)q7.x * D128 + tid];
        float hF = hb[(size_t)q7.z * D128 + tid];
        a0 = fmaf(__int_as_float(q0.y), h0, a0);
        a1 = fmaf(__int_as_float(q0.w), h1, a1);
        a2 = fmaf(__int_as_float(q1.y), h2, a2);
        a3 = fmaf(__int_as_float(q1.w), h3, a3);
        a0 = fmaf(__int_as_float(q2.y), h4, a0);
        a1 = fmaf(__int_as_float(q2.w), h5, a1);
        a2 = fmaf(__int_as_float(q3.y), h6, a2);
        a3 = fmaf(__int_as_float(q3.w), h7, a3);
        a0 = fmaf(__int_as_float(q4.y), h8, a0);
        a1 = fmaf(__int_as_float(q4.w), h9, a1);
        a2 = fmaf(__int_as_float(q5.y), hA, a2);
        a3 = fmaf(__int_as_float(q5.w), hB, a3);
        a0 = fmaf(__int_as_float(q6.y), hC, a0);
        a1 = fmaf(__int_as_float(q6.w), hD, a1);
        a2 = fmaf(__int_as_float(q7.y), hE, a2);
        a3 = fmaf(__int_as_float(q7.w), hF, a3);
    }
    for (; i + 8 <= end; i += 8) {
        int4 q0 = *(const int4*)(sp + i);
        int4 q1 = *(const int4*)(sp + i + 2);
        int4 q2 = *(const int4*)(sp + i + 4);
        int4 q3 = *(const int4*)(sp + i + 6);
        float h0 = hb[(size_t)q0.x * D128 + tid];
        float h1 = hb[(size_t)q0.z * D128 + tid];
        float h2 = hb[(size_t)q1.x * D128 + tid];
        float h3 = hb[(size_t)q1.z * D128 + tid];
        float h4 = hb[(size_t)q2.x * D128 + tid];
        float h5 = hb[(size_t)q2.z * D128 + tid];
        float h6 = hb[(size_t)q3.x * D128 + tid];
        float h7 = hb[(size_t)q3.z * D128 + tid];
        a0 = fmaf(__int_as_float(q0.y), h0, a0);
        a1 = fmaf(__int_as_float(q0.w), h1, a1);
        a2 = fmaf(__int_as_float(q1.y), h2, a2);
        a3 = fmaf(__int_as_float(q1.w), h3, a3);
        a0 = fmaf(__int_as_float(q2.y), h4, a0);
        a1 = fmaf(__int_as_float(q2.w), h5, a1);
        a2 = fmaf(__int_as_float(q3.y), h6, a2);
        a3 = fmaf(__int_as_float(q3.w), h7, a3);
    }
    for (; i + 4 <= end; i += 4) {
        int2 p0 = sp[i], p1 = sp[i + 1], p2 = sp[i + 2], p3 = sp[i + 3];
        a0 = fmaf(__int_as_float(p0.y), hb[(size_t)p0.x * D128 + tid], a0);
        a1 = fmaf(__int_as_float(p1.y), hb[(size_t)p1.x * D128 + tid], a1);
        a2 = fmaf(__int_as_float(p2.y), hb[(size_t)p2.x * D128 + tid], a2);
        a3 = fmaf(__int_as_float(p3.y), hb[(size_t)p3.x * D128 + tid], a3);
    }
    for (; i < end; ++i)
        a0 = fmaf(__int_as_float(sp[i].y), hb[(size_t)sp[i].x * D128 + tid], a0);
    float v = (a0 + a1) + (a2 + a3);
    outbuf[(size_t)nf * D128 + tid] = fmaxf(v + ba.b[view][tid], 0.f);
}

// ---------------------------------------------------------------------------
// unified multi-segment GEMM: C[M,N] = A[M,K] @ W[N,K]^T (+bias, relu)
// ---------------------------------------------------------------------------
struct GSeg {
    const float* A;
    const float* W;
    const float* bias;
    float* C;
    int M, N, K, rowblks, blk0, relu;
};
struct GArgs { GSeg s[4]; int nseg; };

__global__ __launch_bounds__(256) void gemm_b(GArgs ga) {
    __shared__ float xs[32 * 64];
    __shared__ float wsm[128 * 64];
    int si = 0;
    while (si + 1 < ga.nseg && (int)blockIdx.x >= ga.s[si + 1].blk0) ++si;
    const GSeg S = ga.s[si];
    const int lb = blockIdx.x - S.blk0;
    const int rb = lb % S.rowblks, cb = lb / S.rowblks;
    const int row0 = rb * 32, col0 = cb * 128;
    const int tid = threadIdx.x;
    const int r0 = (tid >> 5) << 2;
    const int c0 = tid & 31;
    const int csw = (c0 & 7) << 2;
    float acc[4][4] = {};
    for (int kc = 0; kc < S.K; kc += 64) {
#pragma unroll
        for (int it = 0; it < 2; ++it) {
            int idx = tid + it * 256;
            int r = idx >> 4, k4 = (idx & 15) << 2;
            int gr = row0 + r;
            if (gr > S.M - 1) gr = S.M - 1;
            *(float4*)(xs + r * 64 + k4) =
                *(const float4*)(S.A + (size_t)gr * S.K + kc + k4);
        }
#pragma unroll
        for (int it = 0; it < 8; ++it) {
            int idx = tid + it * 256;
            int c = idx >> 4, k4 = (idx & 15) << 2;
            *(float4*)(wsm + c * 64 + (k4 ^ ((c & 7) << 2))) =
                *(const float4*)(S.W + (size_t)(col0 + c) * S.K + kc + k4);
        }
        __syncthreads();
#pragma unroll
        for (int k4 = 0; k4 < 64; k4 += 4) {
            float4 a0 = *(const float4*)(xs + (r0 + 0) * 64 + k4);
            float4 a1 = *(const float4*)(xs + (r0 + 1) * 64 + k4);
            float4 a2 = *(const float4*)(xs + (r0 + 2) * 64 + k4);
            float4 a3 = *(const float4*)(xs + (r0 + 3) * 64 + k4);
            const int sk = k4 ^ csw;
            float4 w0 = *(const float4*)(wsm + (c0 + 0) * 64 + sk);
            float4 w1 = *(const float4*)(wsm + (c0 + 32) * 64 + sk);
            float4 w2 = *(const float4*)(wsm + (c0 + 64) * 64 + sk);
            float4 w3 = *(const float4*)(wsm + (c0 + 96) * 64 + sk);
#define FMA4(i, av)                                                   \
            acc[i][0] = fmaf(av.x, w0.x, acc[i][0]); acc[i][0] = fmaf(av.y, w0.y, acc[i][0]); \
            acc[i][0] = fmaf(av.z, w0.z, acc[i][0]); acc[i][0] = fmaf(av.w, w0.w, acc[i][0]); \
            acc[i][1] = fmaf(av.x, w1.x, acc[i][1]); acc[i][1] = fmaf(av.y, w1.y, acc[i][1]); \
            acc[i][1] = fmaf(av.z, w1.z, acc[i][1]); acc[i][1] = fmaf(av.w, w1.w, acc[i][1]); \
            acc[i][2] = fmaf(av.x, w2.x, acc[i][2]); acc[i][2] = fmaf(av.y, w2.y, acc[i][2]); \
            acc[i][2] = fmaf(av.z, w2.z, acc[i][2]); acc[i][2] = fmaf(av.w, w2.w, acc[i][2]); \
            acc[i][3] = fmaf(av.x, w3.x, acc[i][3]); acc[i][3] = fmaf(av.y, w3.y, acc[i][3]); \
            acc[i][3] = fmaf(av.z, w3.z, acc[i][3]); acc[i][3] = fmaf(av.w, w3.w, acc[i][3]);
            FMA4(0, a0) FMA4(1, a1) FMA4(2, a2) FMA4(3, a3)
#undef FMA4
        }
        __syncthreads();
    }
#pragma unroll
    for (int i = 0; i < 4; ++i) {
        int gr = row0 + r0 + i;
        if (gr < S.M) {
#pragma unroll
            for (int j = 0; j < 4; ++j) {
                int gc = col0 + c0 + 32 * j;
                float v = acc[i][j];
                if (S.bias) v += S.bias[gc];
                if (S.relu) v = fmaxf(v, 0.f);
                S.C[(size_t)gr * S.N + gc] = v;
            }
        }
    }
}

// ---------------------------------------------------------------------------
// channel sums + attention scales + fused concat
// ---------------------------------------------------------------------------
struct SumArgs {
    const float* p[8];
    int cnt[8];
};

__global__ __launch_bounds__(256) void sum8_kernel(SumArgs args, float* __restrict__ sums) {
    __shared__ float red[256];
    const int ch = blockIdx.y;
    const float* x = args.p[ch];
    const int count = args.cnt[ch];
    float s = 0.f;
    for (int i = blockIdx.x * 256 + threadIdx.x; i < count; i += gridDim.x * 256) s += x[i];
    red[threadIdx.x] = s;
    __syncthreads();
    for (int off = 128; off > 0; off >>= 1) {
        if (threadIdx.x < off) red[threadIdx.x] += red[threadIdx.x + off];
        __syncthreads();
    }
    if (threadIdx.x == 0) atomicAdd(&sums[ch], red[0]);
}

__global__ void att_kernel(const float* __restrict__ sums,
                           const float* __restrict__ mW1, const float* __restrict__ mb1,
                           const float* __restrict__ mW2, const float* __restrict__ mb2,
                           const float* __restrict__ dW1, const float* __restrict__ db1,
                           const float* __restrict__ dW2, const float* __restrict__ db2,
                           float* __restrict__ scales) {
    if (threadIdx.x != 0 || blockIdx.x != 0) return;
    float mean[4], a[4];
    const float invM = 1.0f / (128.f * (float)NM_);
    for (int c = 0; c < 4; ++c) mean[c] = sums[c] * invM;
    for (int i = 0; i < 4; ++i) {
        float v = mb1[i];
        for (int j = 0; j < 4; ++j) v += mW1[i * 4 + j] * mean[j];
        a[i] = fmaxf(v, 0.f);
    }
    for (int c = 0; c < 4; ++c) {
        float v = mb2[c];
        for (int j = 0; j < 4; ++j) v += mW2[c * 4 + j] * a[j];
        scales[c] = 1.f / (1.f + expf(-v));
    }
    const float invD = 1.0f / (128.f * (float)ND_);
    float md[2] = {(sums[4] + sums[6]) * invD, (sums[5] + sums[7]) * invD};
    float ad[2];
    for (int i = 0; i < 2; ++i) {
        float v = db1[i];
        for (int j = 0; j < 2; ++j) v += dW1[i * 2 + j] * md[j];
        ad[i] = fmaxf(v, 0.f);
    }
    for (int c = 0; c < 2; ++c) {
        float v = db2[c];
        for (int j = 0; j < 2; ++j) v += dW2[c * 2 + j] * ad[j];
        scales[4 + c] = 1.f / (1.f + expf(-v));
    }
}

#define MCAT (NM_ * 512)
#define DCAT (ND_ * 256)

__global__ void cat_all(const float* __restrict__ l1, const float* __restrict__ l2,
                        const float* __restrict__ scales, float* __restrict__ catm,
                        float* __restrict__ catd) {
    int idx = blockIdx.x * 256 + threadIdx.x;
    if (idx < MCAT) {
        int i = idx >> 9;
        int k = idx & 511;
        int c = k >> 7;
        int j = k & 127;
        const float* p = (c == 0) ? l1 : (c == 1) ? l2
                         : (c == 2) ? l1 + (size_t)1043 * D128 : l2 + (size_t)1043 * D128;
        catm[idx] = fmaxf(scales[c] * p[(size_t)i * D128 + j], 0.f);
    } else if (idx < MCAT + DCAT) {
        int t = idx - MCAT;
        int i = t >> 8;
        int k = t & 255;
        int c = k >> 7;
        int j = k & 127;
        const float* pa = (c ? l2 : l1) + (size_t)2086 * D128;
        const float* pb = (c ? l2 : l1) + (size_t)4252 * D128;
        catd[t] = fmaxf(scales[4 + c] * (pa[(size_t)i * D128 + j] + pb[(size_t)i * D128 + j]), 0.f);
    }
}

// ---------------------------------------------------------------------------
extern "C" void kernel_launch(void* const* d_in, const int* in_sizes, int n_in,
                              void* d_out, int out_size, void* d_ws, size_t ws_size,
                              hipStream_t stream) {
    const float* mirna_x = (const float*)d_in[0];
    const float* drug_x  = (const float*)d_in[1];
    float* out = (float*)d_out;
    (void)in_sizes; (void)n_in; (void)out_size; (void)ws_size;

    char* ws = (char*)d_ws;
    auto AL = [](size_t x) { return (x + 255) & ~(size_t)255; };
    size_t o = 0;
    int2* spair = (int2*)(ws + o);   o += AL((size_t)ETOT * 8);
    int* cnt = (int*)(ws + o);       o += AL((size_t)NTOT * 4);
    int* rowptr = (int*)(ws + o);    o += AL((size_t)(NTOT + 4) * 4);
    float* dinv = (float*)(ws + o);  o += AL((size_t)NTOT * 4);
    float* sums = (float*)(ws + o);  o += 256;
    float* scales = (float*)(ws + o); o += 256;
    float* hbuf = (float*)(ws + o);  o += AL((size_t)NTOT * D128 * 4);
    float* l1out = (float*)(ws + o); o += AL((size_t)NTOT * D128 * 4);
    float* l2out = (float*)(ws + o); o += AL((size_t)NTOT * D128 * 4);
    // overlaid region R: {pcnt,pdeg,cum} then {catb,fush1}
    const size_t R = o;
    int*   pcnt = (int*)(ws + R);
    float* pdeg = (float*)(ws + R + AL((size_t)NBH * NTOT * 4));
    int*   cum  = (int*)(ws + R + 2 * AL((size_t)NBH * NTOT * 4));
    float* catb_m = (float*)(ws + R);
    float* catb_d = (float*)(ws + R + AL((size_t)NM_ * 512 * 4));
    float* fush1_m = (float*)(ws + R + AL((size_t)NM_ * 512 * 4) + AL((size_t)ND_ * 256 * 4));
    float* fush1_d = fush1_m + (size_t)NM_ * 256;

    ViewArgs va;
    const int vb_in[4] = {2, 8, 14, 20};
    int nn[4] = {NM_, NM_, ND_, ND_};
    int ee[4] = {EM_, EM_, ED_, ED_};
    int cn = 0, ce = 0;
    for (int v = 0; v < 4; ++v) {
        va.edge[v] = (const int*)d_in[vb_in[v]];
        va.w[v] = (const float*)d_in[vb_in[v] + 1];
        va.n[v] = nn[v];
        va.E[v] = ee[v];
        va.cumn[v] = cn;
        va.cumE[v] = ce;
        va.rpo[v] = cn + v;
        cn += nn[v];
        ce += ee[v];
    }
    va.cumn[4] = cn;
    va.cumE[4] = ce;

    hipMemsetAsync(sums, 0, 8 * 4, stream);

    // ---- CSR build (all views) ----
    hist_b<<<256, 1024, 0, stream>>>(va, pcnt, pdeg);
    colred_b<<<(NTOT + 255) / 256, 256, 0, stream>>>(va, pcnt, pdeg, cnt, dinv);
    scan_b<<<4, 256, 0, stream>>>(va, cnt, rowptr);
    cum_b<<<(NTOT + 255) / 256, 256, 0, stream>>>(va, pcnt, rowptr, cum);
    fill2_b<<<256, 1024, 0, stream>>>(va, dinv, cum, spair);

    // ---- layer GEMMs + fused aggregation ----
    auto feat_gemm = [&](int layer, const float* l1src) {
        GArgs ga;
        ga.nseg = 4;
        int blk = 0;
        for (int v = 0; v < 4; ++v) {
            GSeg& S = ga.s[v];
            S.A = (layer == 1) ? ((v < 2) ? mirna_x : drug_x)
                               : l1src + (size_t)va.cumn[v] * D128;
            S.W = (const float*)d_in[vb_in[v] + (layer == 1 ? 2 : 4)];
            S.bias = nullptr;
            S.C = hbuf + (size_t)va.cumn[v] * D128;
            S.M = va.n[v]; S.N = 128; S.K = 128;
            S.rowblks = (va.n[v] + 31) / 32;
            S.blk0 = blk; S.relu = 0;
            blk += S.rowblks;
        }
        gemm_b<<<blk, 256, 0, stream>>>(ga);
    };
    BiasArr b1, b2;
    for (int v = 0; v < 4; ++v) {
        b1.b[v] = (const float*)d_in[vb_in[v] + 3];
        b2.b[v] = (const float*)d_in[vb_in[v] + 5];
    }

    feat_gemm(1, nullptr);
    agg_b<<<NTOT, 128, 0, stream>>>(va, spair, rowptr, hbuf, b1, l1out);
    feat_gemm(2, l1out);
    agg_b<<<NTOT, 128, 0, stream>>>(va, spair, rowptr, hbuf, b2, l2out);

    // ---- channel sums -> attention scales ----
    SumArgs sa;
    sa.p[0] = l1out;                      sa.p[1] = l2out;
    sa.p[2] = l1out + (size_t)1043 * 128; sa.p[3] = l2out + (size_t)1043 * 128;
    sa.p[4] = l1out + (size_t)2086 * 128; sa.p[5] = l2out + (size_t)2086 * 128;
    sa.p[6] = l1out + (size_t)4252 * 128; sa.p[7] = l2out + (size_t)4252 * 128;
    sa.cnt[0] = sa.cnt[1] = sa.cnt[2] = sa.cnt[3] = NM_ * D128;
    sa.cnt[4] = sa.cnt[5] = sa.cnt[6] = sa.cnt[7] = ND_ * D128;
    sum8_kernel<<<dim3(16, 8), 256, 0, stream>>>(sa, sums);
    att_kernel<<<1, 64, 0, stream>>>(sums,
        (const float*)d_in[26], (const float*)d_in[27], (const float*)d_in[28], (const float*)d_in[29],
        (const float*)d_in[30], (const float*)d_in[31], (const float*)d_in[32], (const float*)d_in[33],
        scales);

    // ---- concat (scaled, fused m+d) ----
    cat_all<<<(MCAT + DCAT + 255) / 256, 256, 0, stream>>>(l1out, l2out, scales, catb_m, catb_d);

    // ---- fusion GEMMs (m + d batched) ----
    {
        GArgs ga;
        ga.nseg = 2;
        ga.s[0] = {catb_m, (const float*)d_in[34], (const float*)d_in[35], fush1_m,
                   NM_, 256, 512, 33, 0, 1};
        ga.s[1] = {catb_d, (const float*)d_in[38], (const float*)d_in[39], fush1_d,
                   ND_, 256, 256, 68, 66, 1};
        gemm_b<<<66 + 136, 256, 0, stream>>>(ga);
    }
    {
        GArgs ga;
        ga.nseg = 2;
        ga.s[0] = {fush1_m, (const float*)d_in[36], (const float*)d_in[37], out,
                   NM_, 128, 256, 33, 0, 1};
        ga.s[1] = {fush1_d, (const float*)d_in[40], (const float*)d_in[41],
                   out + (size_t)NM_ * D128, ND_, 128, 256, 68, 33, 1};
        gemm_b<<<33 + 68, 256, 0, stream>>>(ga);
    }
}